// Round 1
// baseline (938.648 us; speedup 1.0000x reference)
//
#include <hip/hip_runtime.h>
#include <hip/hip_bf16.h>

#define BATCH 4096
#define FIELDS_ 39
#define NUMF 13
#define CATF 26
#define DD 16
#define MM 16
#define VV 100000
#define DEEP_ 400
#define QQ 741
#define QPAD 768
#define KE 624      // FIELDS*D
#define N1 6400     // DEEP*M (reordered n = k*16 + m)
#define EPS_ 1e-5f

// workspace layout (float offsets)
#define OFF_FM2   0
#define OFF_A     (BATCH*KE)                 // A[b, qpad] = pair_dot*gc (zero-padded)
#define OFF_T     (OFF_A + BATCH*QPAD)       // t[b, m] = softmax(ga)*t2sum
#define OFF_W     (OFF_T + BATCH*MM)         // Wr2[q, k*16+m] = fi_w[(q*16+m)*400+k]
#define OFF_TH    (OFF_W + QPAD*N1)          // th_pre[b, k]
#define OFF_EMB   (OFF_TH + BATCH*DEEP_)     // emb_pre[b, k]
#define OFF_ACC   (OFF_EMB + BATCH*DEEP_)    // col sums (800) + col sumsq (800)
#define OFF_T2S   (OFF_ACC + 1600)           // t2sum[16]
#define OFF_T3D   (OFF_T2S + 16)             // T3diag[d*16+m]

__global__ void kprep(const float* T3, const float* T2, float* ws) {
    int tid = threadIdx.x;
    if (tid < MM) {
        float s = 0.f;
        for (int j = 0; j < DD * DD; ++j) s += T2[tid * DD * DD + j];
        ws[OFF_T2S + tid] = s;
    }
    if (tid < DD * MM) {
        int d = tid >> 4, m = tid & 15;
        ws[OFF_T3D + tid] = T3[(d * MM + m) * DD + d];
    }
}

__global__ void kwr2(const float* fi_w, float* ws) {
    int idx = blockIdx.x * 256 + threadIdx.x;   // < QPAD*N1
    int q = idx / N1;
    int n = idx - q * N1;
    int k = n >> 4, m = n & 15;
    float v = (q < QQ) ? fi_w[(q * MM + m) * DEEP_ + k] : 0.f;
    ws[OFF_W + idx] = v;
}

__global__ void kfm2(const int* xi, const float* xv, const float* emb, float* ws) {
    int b = blockIdx.x;
    for (int e = threadIdx.x; e < KE; e += 256) {
        int f = e >> 4, d = e & 15;
        float v;
        if (f < NUMF) {
            v = xv[b * NUMF + f] * emb[(long)f * VV * DD + d];
        } else {
            int c = f - NUMF;
            int idxv = xi[b * CATF + c];
            v = emb[((long)(NUMF + c) * VV + idxv) * DD + d];
        }
        ws[OFF_FM2 + b * KE + e] = v;
    }
}

__global__ void k1(const float* gc, float* ws) {
    __shared__ float row[KE];
    __shared__ float hsh[DD];
    __shared__ float gash[MM];
    int b = blockIdx.x, tid = threadIdx.x;
    for (int e = tid; e < KE; e += 256) row[e] = ws[OFF_FM2 + b * KE + e];
    __syncthreads();
    if (tid < DD) {
        float s = 0.f, s2 = 0.f;
        for (int f = 0; f < FIELDS_; ++f) { float v = row[f * DD + tid]; s += v; s2 += v * v; }
        hsh[tid] = 0.5f * (s * s - s2);   // FM identity: sum_{i<j} x_i x_j
    }
    __syncthreads();
    if (tid < MM) {
        float g = 0.f;
        for (int d = 0; d < DD; ++d) g += hsh[d] * ws[OFF_T3D + d * MM + tid];
        gash[tid] = g;
    }
    __syncthreads();
    if (tid < MM) {
        float mx = -1e30f;
        for (int m = 0; m < MM; ++m) mx = fmaxf(mx, gash[m]);
        float se = 0.f;
        for (int m = 0; m < MM; ++m) se += expf(gash[m] - mx);
        float tv = expf(gash[tid] - mx) / se * ws[OFF_T2S + tid];
        ws[OFF_T + b * MM + tid] = tv;
    }
    for (int q = tid; q < QPAD; q += 256) {
        float av = 0.f;
        if (q < QQ) {
            int i = 0, qq = q, cnt = FIELDS_ - 1;
            while (qq >= cnt) { qq -= cnt; ++i; cnt = FIELDS_ - 1 - i; }
            int j = i + 1 + qq;
            float dot = 0.f;
            for (int d = 0; d < DD; ++d) dot += row[i * DD + d] * row[j * DD + d];
            av = dot * gc[q];
        }
        ws[OFF_A + b * QPAD + q] = av;
    }
}

// Fused GEMM: th_pre[b,k] = sum_m t[b,m] * (A @ Wr2)[b, k*16+m]
// tile: 64 rows x 256 cols, 256 threads, micro 4x16 (16 cols = one k-group)
#define BM 64
#define BN 256
#define BK 16
__global__ __launch_bounds__(256) void kgemm(float* ws) {
    __shared__ float As[BK][BM];
    __shared__ float Wl[BK][BN];
    int n0 = blockIdx.x * BN;
    int b0 = blockIdx.y * BM;
    int tid = threadIdx.x;
    int tr = tid >> 4, tc = tid & 15;
    float acc[4][16];
#pragma unroll
    for (int r = 0; r < 4; ++r)
#pragma unroll
        for (int c = 0; c < 16; ++c) acc[r][c] = 0.f;

    const float* Ag = ws + OFF_A;
    const float* Wg = ws + OFF_W;
    int lr = tid >> 2, lkb = (tid & 3) * 4;       // A tile load: row, k-quad
    int wrow = tid >> 6, wcol = (tid & 63) * 4;   // W tile load

    for (int k0 = 0; k0 < QPAD; k0 += BK) {
        float4 a4 = *(const float4*)&Ag[(b0 + lr) * QPAD + k0 + lkb];
        As[lkb + 0][lr] = a4.x; As[lkb + 1][lr] = a4.y;
        As[lkb + 2][lr] = a4.z; As[lkb + 3][lr] = a4.w;
#pragma unroll
        for (int p = 0; p < 4; ++p) {
            int rr = wrow + p * 4;
            float4 w4 = *(const float4*)&Wg[(long)(k0 + rr) * N1 + n0 + wcol];
            *(float4*)&Wl[rr][wcol] = w4;
        }
        __syncthreads();
#pragma unroll
        for (int kk = 0; kk < BK; ++kk) {
            float4 a = *(const float4*)&As[kk][tr * 4];
            float av[4] = {a.x, a.y, a.z, a.w};
            float4 w0 = *(const float4*)&Wl[kk][tc * 16 + 0];
            float4 w1 = *(const float4*)&Wl[kk][tc * 16 + 4];
            float4 w2 = *(const float4*)&Wl[kk][tc * 16 + 8];
            float4 w3 = *(const float4*)&Wl[kk][tc * 16 + 12];
            float wv[16] = {w0.x, w0.y, w0.z, w0.w, w1.x, w1.y, w1.z, w1.w,
                            w2.x, w2.y, w2.z, w2.w, w3.x, w3.y, w3.z, w3.w};
#pragma unroll
            for (int r = 0; r < 4; ++r)
#pragma unroll
                for (int c = 0; c < 16; ++c) acc[r][c] += av[r] * wv[c];
        }
        __syncthreads();
    }
    int kcol = (n0 >> 4) + tc;
#pragma unroll
    for (int r = 0; r < 4; ++r) {
        int brow = b0 + tr * 4 + r;
        const float* trow = ws + OFF_T + brow * MM;
        float s = 0.f;
#pragma unroll
        for (int m = 0; m < MM; ++m) s += acc[r][m] * trow[m];
        ws[OFF_TH + brow * DEEP_ + kcol] = s;
    }
}

// emb branch GEMM: emb_pre[b,k] = fm2[b,:624] @ emb_w[:,k]; 64x64 tile, micro 4x4
__global__ __launch_bounds__(256) void kegemm(const float* emb_w, float* ws) {
    __shared__ float As[16][64];
    __shared__ float Bs[16][64];
    int n0 = blockIdx.x * 64;
    int b0 = blockIdx.y * 64;
    int tid = threadIdx.x;
    int tr = tid >> 4, tc = tid & 15;
    float acc[4][4];
#pragma unroll
    for (int r = 0; r < 4; ++r)
#pragma unroll
        for (int c = 0; c < 4; ++c) acc[r][c] = 0.f;

    int lr = tid >> 2, lkb = (tid & 3) * 4;
    int brow = tid >> 4, bcol = (tid & 15) * 4;

    for (int k0 = 0; k0 < KE; k0 += 16) {
        float4 a4 = *(const float4*)&ws[OFF_FM2 + (b0 + lr) * KE + k0 + lkb];
        As[lkb + 0][lr] = a4.x; As[lkb + 1][lr] = a4.y;
        As[lkb + 2][lr] = a4.z; As[lkb + 3][lr] = a4.w;
        int gcol = n0 + bcol;
        float4 b4 = {0.f, 0.f, 0.f, 0.f};
        if (gcol + 3 < DEEP_) {
            b4 = *(const float4*)&emb_w[(k0 + brow) * DEEP_ + gcol];
        } else {
            float* bp = (float*)&b4;
            for (int e = 0; e < 4; ++e)
                if (gcol + e < DEEP_) bp[e] = emb_w[(k0 + brow) * DEEP_ + gcol + e];
        }
        *(float4*)&Bs[brow][bcol] = b4;
        __syncthreads();
#pragma unroll
        for (int kk = 0; kk < 16; ++kk) {
            float4 a = *(const float4*)&As[kk][tr * 4];
            float4 bb = *(const float4*)&Bs[kk][tc * 4];
            float av[4] = {a.x, a.y, a.z, a.w};
            float bv[4] = {bb.x, bb.y, bb.z, bb.w};
#pragma unroll
            for (int r = 0; r < 4; ++r)
#pragma unroll
                for (int c = 0; c < 4; ++c) acc[r][c] += av[r] * bv[c];
        }
        __syncthreads();
    }
#pragma unroll
    for (int r = 0; r < 4; ++r)
#pragma unroll
        for (int c = 0; c < 4; ++c) {
            int col = n0 + tc * 4 + c;
            if (col < DEEP_) ws[OFF_EMB + (b0 + tr * 4 + r) * DEEP_ + col] = acc[r][c];
        }
}

__global__ void kstats(float* ws) {
    int r0 = blockIdx.x * 128;
    int tid = threadIdx.x;
    float s[4] = {0, 0, 0, 0}, s2[4] = {0, 0, 0, 0};
    for (int r = r0; r < r0 + 128; ++r) {
#pragma unroll
        for (int ci = 0; ci < 4; ++ci) {
            int c = tid + ci * 256;
            if (c < 800) {
                float x = (c < DEEP_) ? ws[OFF_TH + r * DEEP_ + c]
                                      : ws[OFF_EMB + r * DEEP_ + (c - DEEP_)];
                s[ci] += x; s2[ci] += x * x;
            }
        }
    }
#pragma unroll
    for (int ci = 0; ci < 4; ++ci) {
        int c = tid + ci * 256;
        if (c < 800) {
            atomicAdd(&ws[OFF_ACC + c], s[ci]);
            atomicAdd(&ws[OFF_ACC + 800 + c], s2[ci]);
        }
    }
}

__global__ __launch_bounds__(256) void kfinal(const float* fig, const float* fibeta,
                                              const float* eg, const float* ebeta,
                                              const float* fcw, const float* fcb,
                                              const float* ws, float* out) {
    int b = blockIdx.x, tid = threadIdx.x;
    float part = 0.f;
    for (int c = tid; c < 800; c += 256) {
        float x, g, be;
        if (c < DEEP_) { x = ws[OFF_TH + b * DEEP_ + c]; g = fig[c]; be = fibeta[c]; }
        else { int cc = c - DEEP_; x = ws[OFF_EMB + b * DEEP_ + cc]; g = eg[cc]; be = ebeta[cc]; }
        float sm = ws[OFF_ACC + c], sq = ws[OFF_ACC + 800 + c];
        float mean = sm * (1.f / BATCH);
        float var = sq * (1.f / BATCH) - mean * mean;
        float rstd = rsqrtf(var + EPS_);
        float v = fmaxf(g * (x - mean) * rstd + be, 0.f);
        part += v * fcw[c];
    }
    __shared__ float red[4];
#pragma unroll
    for (int off = 32; off > 0; off >>= 1) part += __shfl_down(part, off, 64);
    if ((tid & 63) == 0) red[tid >> 6] = part;
    __syncthreads();
    if (tid == 0) {
        float tot = red[0] + red[1] + red[2] + red[3] + fcb[0];
        out[b] = 1.f / (1.f + expf(-tot));
    }
}

extern "C" void kernel_launch(void* const* d_in, const int* in_sizes, int n_in,
                              void* d_out, int out_size, void* d_ws, size_t ws_size,
                              hipStream_t stream) {
    const int*   xi    = (const int*)d_in[0];
    const float* xv    = (const float*)d_in[1];
    const float* emb   = (const float*)d_in[2];
    const float* T3    = (const float*)d_in[3];
    const float* T2    = (const float*)d_in[4];
    const float* gc    = (const float*)d_in[5];
    const float* fi_w  = (const float*)d_in[6];
    const float* fig   = (const float*)d_in[8];
    const float* fibt  = (const float*)d_in[9];
    const float* emb_w = (const float*)d_in[10];
    const float* eg    = (const float*)d_in[12];
    const float* ebt   = (const float*)d_in[13];
    const float* fcw   = (const float*)d_in[14];
    const float* fcb   = (const float*)d_in[15];
    float* ws = (float*)d_ws;
    float* out = (float*)d_out;

    hipLaunchKernelGGL(kprep, dim3(1), dim3(256), 0, stream, T3, T2, ws);
    hipLaunchKernelGGL(kwr2, dim3(QPAD * N1 / 256), dim3(256), 0, stream, fi_w, ws);
    hipLaunchKernelGGL(kfm2, dim3(BATCH), dim3(256), 0, stream, xi, xv, emb, ws);
    hipLaunchKernelGGL(k1, dim3(BATCH), dim3(256), 0, stream, gc, ws);
    hipLaunchKernelGGL(kgemm, dim3(N1 / BN, BATCH / BM), dim3(256), 0, stream, ws);
    hipLaunchKernelGGL(kegemm, dim3(7, BATCH / 64), dim3(256), 0, stream, emb_w, ws);
    hipMemsetAsync(ws + OFF_ACC, 0, 1600 * sizeof(float), stream);
    hipLaunchKernelGGL(kstats, dim3(32), dim3(256), 0, stream, ws);
    hipLaunchKernelGGL(kfinal, dim3(BATCH), dim3(256), 0, stream,
                       fig, fibt, eg, ebt, fcw, fcb, ws, out);
}

// Round 2
// 338.585 us; speedup vs baseline: 2.7723x; 2.7723x over previous
//
#include <hip/hip_runtime.h>
#include <hip/hip_bf16.h>

#define BATCH 4096
#define FIELDS_ 39
#define NUMF 13
#define CATF 26
#define DD 16
#define MM 16
#define VV 100000
#define DEEP_ 400
#define QQ 741
#define QPAD 768
#define KE 624      // FIELDS*D
#define N1 6400     // DEEP*M (n = kcol*16 + m)
#define NKT 24      // QPAD/32 k-tiles
#define EPS_ 1e-5f

// workspace layout (float offsets)
#define OFF_FM2   0
#define OFF_ABF   (BATCH*KE)                   // bf16 A[b][q], QPAD stride (ushort)
#define OFF_T     (OFF_ABF + BATCH*QPAD/2)     // t[b, m] = softmax(ga)*t2sum (f32)
#define OFF_W2    (OFF_T + BATCH*MM)           // bf16 W2[kt][n][kk] (ushort)
#define OFF_TH    (OFF_W2 + NKT*N1*32/2)       // th_pre[b, k] f32
#define OFF_EMB   (OFF_TH + BATCH*DEEP_)       // emb_pre[b, k] f32
#define OFF_ACC   (OFF_EMB + BATCH*DEEP_)      // col sums (800) + col sumsq (800)
#define OFF_T2S   (OFF_ACC + 1600)
#define OFF_T3D   (OFF_T2S + 16)

typedef __attribute__((ext_vector_type(8))) short bf16x8;
typedef __attribute__((ext_vector_type(4))) float f32x4;

__device__ __forceinline__ ushort f2bf(float v) {
    union { float f; unsigned u; } x; x.f = v;
    unsigned r = x.u + 0x7fff + ((x.u >> 16) & 1);
    return (ushort)(r >> 16);
}

__device__ __forceinline__ void async16(void* lds, const void* g) {
    __builtin_amdgcn_global_load_lds(
        (const __attribute__((address_space(1))) unsigned int*)g,
        (__attribute__((address_space(3))) unsigned int*)lds,
        16, 0, 0);
}

__global__ void kprep(const float* T3, const float* T2, float* ws) {
    int tid = threadIdx.x;
    if (tid < MM) {
        float s = 0.f;
        for (int j = 0; j < DD * DD; ++j) s += T2[tid * DD * DD + j];
        ws[OFF_T2S + tid] = s;
    }
    if (tid < DD * MM) {
        int d = tid >> 4, m = tid & 15;
        ws[OFF_T3D + tid] = T3[(d * MM + m) * DD + d];
    }
}

// W2[kt][n][kk] bf16, q = kt*32+kk, n = kcol*16+m, source fi_w[(q*16+m)*400+kcol]
__global__ void kwr2(const float* fi_w, ushort* W2) {
    int o = blockIdx.x * 256 + threadIdx.x;    // < NKT*N1*32 = 4915200
    int kk = o & 31;
    int nn = (o >> 5) % N1;
    int kt = o / (N1 * 32);
    int q = kt * 32 + kk;
    int kcol = nn >> 4, m = nn & 15;
    float v = (q < QQ) ? fi_w[(q * MM + m) * DEEP_ + kcol] : 0.f;
    W2[o] = f2bf(v);
}

__global__ void kfm2(const int* xi, const float* xv, const float* emb, float* ws) {
    int b = blockIdx.x;
    for (int e = threadIdx.x; e < KE; e += 256) {
        int f = e >> 4, d = e & 15;
        float v;
        if (f < NUMF) {
            v = xv[b * NUMF + f] * emb[(long)f * VV * DD + d];
        } else {
            int c = f - NUMF;
            int idxv = xi[b * CATF + c];
            v = emb[((long)(NUMF + c) * VV + idxv) * DD + d];
        }
        ws[OFF_FM2 + b * KE + e] = v;
    }
}

__global__ void k1(const float* gc, float* ws, ushort* Abf) {
    __shared__ float row[KE];
    __shared__ float hsh[DD];
    __shared__ float gash[MM];
    int b = blockIdx.x, tid = threadIdx.x;
    for (int e = tid; e < KE; e += 256) row[e] = ws[OFF_FM2 + b * KE + e];
    __syncthreads();
    if (tid < DD) {
        float s = 0.f, s2 = 0.f;
        for (int f = 0; f < FIELDS_; ++f) { float v = row[f * DD + tid]; s += v; s2 += v * v; }
        hsh[tid] = 0.5f * (s * s - s2);
    }
    __syncthreads();
    if (tid < MM) {
        float g = 0.f;
        for (int d = 0; d < DD; ++d) g += hsh[d] * ws[OFF_T3D + d * MM + tid];
        gash[tid] = g;
    }
    __syncthreads();
    if (tid < MM) {
        float mx = -1e30f;
        for (int m = 0; m < MM; ++m) mx = fmaxf(mx, gash[m]);
        float se = 0.f;
        for (int m = 0; m < MM; ++m) se += expf(gash[m] - mx);
        float tv = expf(gash[tid] - mx) / se * ws[OFF_T2S + tid];
        ws[OFF_T + b * MM + tid] = tv;
    }
    for (int q = tid; q < QPAD; q += 256) {
        float av = 0.f;
        if (q < QQ) {
            int i = 0, qq = q, cnt = FIELDS_ - 1;
            while (qq >= cnt) { qq -= cnt; ++i; cnt = FIELDS_ - 1 - i; }
            int j = i + 1 + qq;
            float dot = 0.f;
            for (int d = 0; d < DD; ++d) dot += row[i * DD + d] * row[j * DD + d];
            av = dot * gc[q];
        }
        Abf[b * QPAD + q] = f2bf(av);
    }
}

// MFMA GEMM: C[b,n] = A[4096x768] @ W2, fused epilogue th[b,kcol] = sum_m t[b,m]*C[b,kcol*16+m]
// 128x128 tile, BK=32, 4 waves (2x2), each wave 64x64 via 4x4 16x16x32 MFMAs.
__global__ __launch_bounds__(256) void kgemm2(const ushort* __restrict__ Abf,
                                              const ushort* __restrict__ W2,
                                              const float* __restrict__ Tmat,
                                              float* __restrict__ TH) {
    __shared__ ushort Al[128 * 32];   // [row][k] row-major
    __shared__ ushort Bl[128 * 32];   // [col][k] (k contiguous)
    __shared__ float  Tl[128 * 16];
    int tid = threadIdx.x;
    int wid = tid >> 6, lane = tid & 63;
    int n0 = blockIdx.x * 128;
    int b0 = blockIdx.y * 128;
    int wr = wid >> 1, wc = wid & 1;

    // preload t rows for this block's 128 batch rows
    for (int i = tid; i < 128 * 16 / 4; i += 256)
        *(float4*)&Tl[i * 4] = *(const float4*)&Tmat[b0 * 16 + i * 4];

    f32x4 acc[4][4] = {};

    const ushort* Ag = Abf + (long)b0 * QPAD;
    const ushort* Wg = W2 + (long)n0 * 32;
    int kq = lane >> 4;       // 0..3 k-quarter
    int lr = lane & 15;

    for (int kt = 0; kt < NKT; ++kt) {
        // stage A tile (128x32 bf16 = 8KB): chunks c=tid, tid+256
        {
            int c = tid;
            async16(&Al[c * 8], &Ag[(c >> 2) * QPAD + kt * 32 + (c & 3) * 8]);
            c = tid + 256;
            async16(&Al[c * 8], &Ag[(c >> 2) * QPAD + kt * 32 + (c & 3) * 8]);
        }
        // stage B tile (128 cols x 32 k)
        {
            int c = tid;
            async16(&Bl[c * 8], &Wg[((long)kt * N1 + (c >> 2)) * 32 + (c & 3) * 8]);
            c = tid + 256;
            async16(&Bl[c * 8], &Wg[((long)kt * N1 + (c >> 2)) * 32 + (c & 3) * 8]);
        }
        __syncthreads();   // drains vmcnt before barrier (compiler-enforced)

        bf16x8 af[4], bfr[4];
#pragma unroll
        for (int r = 0; r < 4; ++r)
            af[r] = *(bf16x8*)&Al[(wr * 64 + r * 16 + lr) * 32 + kq * 8];
#pragma unroll
        for (int cg = 0; cg < 4; ++cg)
            bfr[cg] = *(bf16x8*)&Bl[(wc * 64 + cg * 16 + lr) * 32 + kq * 8];
#pragma unroll
        for (int r = 0; r < 4; ++r)
#pragma unroll
            for (int cg = 0; cg < 4; ++cg)
                acc[r][cg] = __builtin_amdgcn_mfma_f32_16x16x32_bf16(af[r], bfr[cg], acc[r][cg], 0, 0, 0);
        __syncthreads();
    }

    // epilogue: th[b, kcol] = sum over 16 lanes of acc*t
#pragma unroll
    for (int r = 0; r < 4; ++r) {
#pragma unroll
        for (int cg = 0; cg < 4; ++cg) {
            int kcol = (n0 + wc * 64 + cg * 16) >> 4;
#pragma unroll
            for (int j = 0; j < 4; ++j) {
                int lrow = wr * 64 + r * 16 + kq * 4 + j;
                float v = acc[r][cg][j] * Tl[lrow * 16 + lr];
                v += __shfl_xor(v, 8, 16);
                v += __shfl_xor(v, 4, 16);
                v += __shfl_xor(v, 2, 16);
                v += __shfl_xor(v, 1, 16);
                if (lr == 0) TH[(b0 + lrow) * DEEP_ + kcol] = v;
            }
        }
    }
}

// emb branch GEMM: emb_pre[b,k] = fm2[b,:624] @ emb_w[:,k]; 64x64 tile fp32
__global__ __launch_bounds__(256) void kegemm(const float* emb_w, float* ws) {
    __shared__ float As[16][64];
    __shared__ float Bs[16][64];
    int n0 = blockIdx.x * 64;
    int b0 = blockIdx.y * 64;
    int tid = threadIdx.x;
    int tr = tid >> 4, tc = tid & 15;
    float acc[4][4];
#pragma unroll
    for (int r = 0; r < 4; ++r)
#pragma unroll
        for (int c = 0; c < 4; ++c) acc[r][c] = 0.f;

    int lr = tid >> 2, lkb = (tid & 3) * 4;
    int brow = tid >> 4, bcol = (tid & 15) * 4;

    for (int k0 = 0; k0 < KE; k0 += 16) {
        float4 a4 = *(const float4*)&ws[OFF_FM2 + (b0 + lr) * KE + k0 + lkb];
        As[lkb + 0][lr] = a4.x; As[lkb + 1][lr] = a4.y;
        As[lkb + 2][lr] = a4.z; As[lkb + 3][lr] = a4.w;
        int gcol = n0 + bcol;
        float4 b4 = {0.f, 0.f, 0.f, 0.f};
        if (gcol + 3 < DEEP_) {
            b4 = *(const float4*)&emb_w[(k0 + brow) * DEEP_ + gcol];
        } else {
            float* bp = (float*)&b4;
            for (int e = 0; e < 4; ++e)
                if (gcol + e < DEEP_) bp[e] = emb_w[(k0 + brow) * DEEP_ + gcol + e];
        }
        *(float4*)&Bs[brow][bcol] = b4;
        __syncthreads();
#pragma unroll
        for (int kk = 0; kk < 16; ++kk) {
            float4 a = *(const float4*)&As[kk][tr * 4];
            float4 bb = *(const float4*)&Bs[kk][tc * 4];
            float av[4] = {a.x, a.y, a.z, a.w};
            float bv[4] = {bb.x, bb.y, bb.z, bb.w};
#pragma unroll
            for (int r = 0; r < 4; ++r)
#pragma unroll
                for (int c = 0; c < 4; ++c) acc[r][c] += av[r] * bv[c];
        }
        __syncthreads();
    }
#pragma unroll
    for (int r = 0; r < 4; ++r)
#pragma unroll
        for (int c = 0; c < 4; ++c) {
            int col = n0 + tc * 4 + c;
            if (col < DEEP_) ws[OFF_EMB + (b0 + tr * 4 + r) * DEEP_ + col] = acc[r][c];
        }
}

__global__ void kstats(float* ws) {
    int r0 = blockIdx.x * 128;
    int tid = threadIdx.x;
    float s[4] = {0, 0, 0, 0}, s2[4] = {0, 0, 0, 0};
    for (int r = r0; r < r0 + 128; ++r) {
#pragma unroll
        for (int ci = 0; ci < 4; ++ci) {
            int c = tid + ci * 256;
            if (c < 800) {
                float x = (c < DEEP_) ? ws[OFF_TH + r * DEEP_ + c]
                                      : ws[OFF_EMB + r * DEEP_ + (c - DEEP_)];
                s[ci] += x; s2[ci] += x * x;
            }
        }
    }
#pragma unroll
    for (int ci = 0; ci < 4; ++ci) {
        int c = tid + ci * 256;
        if (c < 800) {
            atomicAdd(&ws[OFF_ACC + c], s[ci]);
            atomicAdd(&ws[OFF_ACC + 800 + c], s2[ci]);
        }
    }
}

__global__ __launch_bounds__(256) void kfinal(const float* fig, const float* fibeta,
                                              const float* eg, const float* ebeta,
                                              const float* fcw, const float* fcb,
                                              const float* ws, float* out) {
    int b = blockIdx.x, tid = threadIdx.x;
    float part = 0.f;
    for (int c = tid; c < 800; c += 256) {
        float x, g, be;
        if (c < DEEP_) { x = ws[OFF_TH + b * DEEP_ + c]; g = fig[c]; be = fibeta[c]; }
        else { int cc = c - DEEP_; x = ws[OFF_EMB + b * DEEP_ + cc]; g = eg[cc]; be = ebeta[cc]; }
        float sm = ws[OFF_ACC + c], sq = ws[OFF_ACC + 800 + c];
        float mean = sm * (1.f / BATCH);
        float var = sq * (1.f / BATCH) - mean * mean;
        float rstd = rsqrtf(var + EPS_);
        float v = fmaxf(g * (x - mean) * rstd + be, 0.f);
        part += v * fcw[c];
    }
    __shared__ float red[4];
#pragma unroll
    for (int off = 32; off > 0; off >>= 1) part += __shfl_down(part, off, 64);
    if ((tid & 63) == 0) red[tid >> 6] = part;
    __syncthreads();
    if (tid == 0) {
        float tot = red[0] + red[1] + red[2] + red[3] + fcb[0];
        out[b] = 1.f / (1.f + expf(-tot));
    }
}

extern "C" void kernel_launch(void* const* d_in, const int* in_sizes, int n_in,
                              void* d_out, int out_size, void* d_ws, size_t ws_size,
                              hipStream_t stream) {
    const int*   xi    = (const int*)d_in[0];
    const float* xv    = (const float*)d_in[1];
    const float* emb   = (const float*)d_in[2];
    const float* T3    = (const float*)d_in[3];
    const float* T2    = (const float*)d_in[4];
    const float* gc    = (const float*)d_in[5];
    const float* fi_w  = (const float*)d_in[6];
    const float* fig   = (const float*)d_in[8];
    const float* fibt  = (const float*)d_in[9];
    const float* emb_w = (const float*)d_in[10];
    const float* eg    = (const float*)d_in[12];
    const float* ebt   = (const float*)d_in[13];
    const float* fcw   = (const float*)d_in[14];
    const float* fcb   = (const float*)d_in[15];
    float* ws = (float*)d_ws;
    ushort* Abf = (ushort*)(ws + OFF_ABF);
    ushort* W2  = (ushort*)(ws + OFF_W2);
    float* out = (float*)d_out;

    hipLaunchKernelGGL(kprep, dim3(1), dim3(256), 0, stream, T3, T2, ws);
    hipLaunchKernelGGL(kwr2, dim3(NKT * N1 * 32 / 256), dim3(256), 0, stream, fi_w, W2);
    hipLaunchKernelGGL(kfm2, dim3(BATCH), dim3(256), 0, stream, xi, xv, emb, ws);
    hipLaunchKernelGGL(k1, dim3(BATCH), dim3(256), 0, stream, gc, ws, Abf);
    hipLaunchKernelGGL(kgemm2, dim3(N1 / 128, BATCH / 128), dim3(256), 0, stream,
                       Abf, W2, ws + OFF_T, ws + OFF_TH);
    hipLaunchKernelGGL(kegemm, dim3(7, BATCH / 64), dim3(256), 0, stream, emb_w, ws);
    hipMemsetAsync(ws + OFF_ACC, 0, 1600 * sizeof(float), stream);
    hipLaunchKernelGGL(kstats, dim3(32), dim3(256), 0, stream, ws);
    hipLaunchKernelGGL(kfinal, dim3(BATCH), dim3(256), 0, stream,
                       fig, fibt, eg, ebt, fcw, fcb, ws, out);
}

// Round 3
// 170.732 us; speedup vs baseline: 5.4978x; 1.9831x over previous
//
#include <hip/hip_runtime.h>
#include <hip/hip_bf16.h>

#define BATCH 4096
#define FIELDS_ 39
#define NUMF 13
#define CATF 26
#define DD 16
#define MM 16
#define VV 100000
#define DEEP_ 400
#define QQ 741
#define QPAD 768
#define KE 624      // FIELDS*D
#define KEP 640     // padded K for emb branch
#define NEP 512     // padded N for emb branch
#define N1 6400     // DEEP*M (n = kcol*16 + m)
#define NKT 24      // QPAD/32
#define NKTE 20     // KEP/32
#define EPS_ 1e-5f

// workspace layout (float offsets)
#define OFF_ABF 0                            // ushort A[b][q] stride QPAD
#define OFF_T   (BATCH*QPAD/2)               // f32 t[b][m]
#define OFF_W2  (OFF_T + BATCH*MM)           // ushort W2[kt][n][kk]
#define OFF_WE  (OFF_W2 + NKT*N1*16)         // ushort WE[kt][n][kk]
#define OFF_FMB (OFF_WE + NKTE*NEP*16)       // ushort fm2[b][k] stride KEP
#define OFF_TH  (OFF_FMB + BATCH*KEP/2)      // f32 th_pre[b][400]
#define OFF_EMB (OFF_TH + BATCH*DEEP_)       // f32 emb_pre[b][400]
#define OFF_ACC (OFF_EMB + BATCH*DEEP_)      // 800 sums + 800 sumsq
#define OFF_T2S (OFF_ACC + 1600)
#define OFF_T3D (OFF_T2S + 16)
#define OFF_QIJ (OFF_T3D + 256)              // int table q -> (i<<8|j)

typedef __attribute__((ext_vector_type(8))) short bf16x8;
typedef __attribute__((ext_vector_type(4))) float f32x4;

__device__ __forceinline__ ushort f2bf(float v) {
    union { float f; unsigned u; } x; x.f = v;
    unsigned r = x.u + 0x7fff + ((x.u >> 16) & 1);
    return (ushort)(r >> 16);
}
__device__ __forceinline__ unsigned pack2(float a, float b) {
    return (unsigned)f2bf(a) | ((unsigned)f2bf(b) << 16);
}
__device__ __forceinline__ void async16(void* lds, const void* g) {
    __builtin_amdgcn_global_load_lds(
        (const __attribute__((address_space(1))) unsigned int*)g,
        (__attribute__((address_space(3))) unsigned int*)lds,
        16, 0, 0);
}

__global__ void kprep(const float* T3, const float* T2, float* ws) {
    int tid = threadIdx.x;
    if (tid < MM) {
        float s = 0.f;
        for (int j = 0; j < DD * DD; ++j) s += T2[tid * DD * DD + j];
        ws[OFF_T2S + tid] = s;
    }
    if (tid < DD * MM) {
        int d = tid >> 4, m = tid & 15;
        ws[OFF_T3D + tid] = T3[(d * MM + m) * DD + d];
    }
    int* qij = (int*)(ws + OFF_QIJ);
    for (int q = tid; q < QPAD; q += 256) {
        int v = 0;
        if (q < QQ) {
            int i = 0, qq = q, cnt = FIELDS_ - 1;
            while (qq >= cnt) { qq -= cnt; ++i; cnt = FIELDS_ - 1 - i; }
            v = (i << 8) | (i + 1 + qq);
        }
        qij[q] = v;
    }
}

// fi_w -> W2[kt][n][kk] bf16; each thread: 8 kk, one 16B store
__global__ void kwr2(const float* __restrict__ fi_w, ushort* __restrict__ W2) {
    int t = blockIdx.x * 256 + threadIdx.x;   // < NKT*N1*4
    int kkb = t & 3;
    int n = (t >> 2) % N1;
    int kt = t / (N1 * 4);
    int kcol = n >> 4, m = n & 15;
    unsigned v[4];
#pragma unroll
    for (int i = 0; i < 4; ++i) {
        int q0 = kt * 32 + kkb * 8 + 2 * i;
        float f0 = (q0 < QQ) ? fi_w[(q0 * MM + m) * DEEP_ + kcol] : 0.f;
        float f1 = (q0 + 1 < QQ) ? fi_w[((q0 + 1) * MM + m) * DEEP_ + kcol] : 0.f;
        v[i] = pack2(f0, f1);
    }
    *(uint4*)&W2[((long)(kt * N1 + n)) * 32 + kkb * 8] = make_uint4(v[0], v[1], v[2], v[3]);
}

// emb_w -> WE[kt][n][kk] bf16 (K padded 624->640, N padded 400->512)
__global__ void kwe(const float* __restrict__ emb_w, ushort* __restrict__ WE) {
    int t = blockIdx.x * 256 + threadIdx.x;   // < NKTE*NEP*4
    int kkb = t & 3;
    int n = (t >> 2) % NEP;
    int kt = t / (NEP * 4);
    unsigned v[4];
#pragma unroll
    for (int i = 0; i < 4; ++i) {
        int k0 = kt * 32 + kkb * 8 + 2 * i;
        float f0 = (k0 < KE && n < DEEP_) ? emb_w[k0 * DEEP_ + n] : 0.f;
        float f1 = (k0 + 1 < KE && n < DEEP_) ? emb_w[(k0 + 1) * DEEP_ + n] : 0.f;
        v[i] = pack2(f0, f1);
    }
    *(uint4*)&WE[((long)(kt * NEP + n)) * 32 + kkb * 8] = make_uint4(v[0], v[1], v[2], v[3]);
}

// fused: gather fm2 -> FMB bf16, FM-identity h, ga, softmax*t2sum -> T, pair dots -> Abf
__global__ __launch_bounds__(256) void kfeat(const int* __restrict__ xi,
                                             const float* __restrict__ xv,
                                             const float* __restrict__ emb,
                                             const float* __restrict__ gc,
                                             float* __restrict__ ws,
                                             ushort* __restrict__ Abf,
                                             ushort* __restrict__ FMB) {
    __shared__ float row[KE];
    __shared__ float hsh[DD];
    __shared__ float gash[MM];
    int b = blockIdx.x, tid = threadIdx.x;
    for (int e = tid; e < KE; e += 256) {
        int f = e >> 4, d = e & 15;
        float v;
        if (f < NUMF) {
            v = xv[b * NUMF + f] * emb[(long)f * VV * DD + d];
        } else {
            int c = f - NUMF;
            int idxv = xi[b * CATF + c];
            v = emb[((long)(NUMF + c) * VV + idxv) * DD + d];
        }
        row[e] = v;
    }
    __syncthreads();
    for (int e = tid; e < KEP; e += 256)
        FMB[(long)b * KEP + e] = (e < KE) ? f2bf(row[e]) : (ushort)0;
    if (tid < DD) {
        float s = 0.f, s2 = 0.f;
        for (int f = 0; f < FIELDS_; ++f) { float v = row[f * DD + tid]; s += v; s2 += v * v; }
        hsh[tid] = 0.5f * (s * s - s2);
    }
    __syncthreads();
    if (tid < MM) {
        float g = 0.f;
        for (int d = 0; d < DD; ++d) g += hsh[d] * ws[OFF_T3D + d * MM + tid];
        gash[tid] = g;
    }
    __syncthreads();
    if (tid < MM) {
        float mx = -1e30f;
        for (int m = 0; m < MM; ++m) mx = fmaxf(mx, gash[m]);
        float se = 0.f;
        for (int m = 0; m < MM; ++m) se += expf(gash[m] - mx);
        ws[OFF_T + b * MM + tid] = expf(gash[tid] - mx) / se * ws[OFF_T2S + tid];
    }
    const int* qij = (const int*)(ws + OFF_QIJ);
    for (int q = tid; q < QPAD; q += 256) {
        float av = 0.f;
        if (q < QQ) {
            int ij = qij[q];
            int i = ij >> 8, j = ij & 255;
            float dot = 0.f;
#pragma unroll
            for (int d = 0; d < DD; ++d) dot += row[i * DD + d] * row[j * DD + d];
            av = dot * gc[q];
        }
        Abf[(long)b * QPAD + q] = f2bf(av);
    }
}

// MFMA GEMM 1: th[b,kcol] = sum_m t[b,m]*(A@W2)[b,kcol*16+m]; fused BN col stats
__global__ __launch_bounds__(256) void kgemm2(const ushort* __restrict__ Abf,
                                              const ushort* __restrict__ W2,
                                              const float* __restrict__ Tmat,
                                              float* __restrict__ TH,
                                              float* __restrict__ ACC) {
    __shared__ ushort Al[128 * 32];
    __shared__ ushort Bl[128 * 32];
    __shared__ float  Tl[128 * 16];
    __shared__ float  sst[2][8];
    int tid = threadIdx.x;
    int wid = tid >> 6, lane = tid & 63;
    int n0 = blockIdx.x * 128;
    int b0 = blockIdx.y * 128;
    int wr = wid >> 1, wc = wid & 1;
    if (tid < 16) sst[tid >> 3][tid & 7] = 0.f;

    for (int i = tid; i < 128 * 16 / 4; i += 256)
        *(float4*)&Tl[i * 4] = *(const float4*)&Tmat[b0 * 16 + i * 4];

    f32x4 acc[4][4] = {};
    const ushort* Ag = Abf + (long)b0 * QPAD;
    const ushort* Wg = W2 + (long)n0 * 32;
    int kq = lane >> 4;
    int lr = lane & 15;

    for (int kt = 0; kt < NKT; ++kt) {
        {
            int c = tid;
            async16(&Al[c * 8], &Ag[(c >> 2) * QPAD + kt * 32 + (c & 3) * 8]);
            c = tid + 256;
            async16(&Al[c * 8], &Ag[(c >> 2) * QPAD + kt * 32 + (c & 3) * 8]);
            c = tid;
            async16(&Bl[c * 8], &Wg[((long)kt * N1 + (c >> 2)) * 32 + (c & 3) * 8]);
            c = tid + 256;
            async16(&Bl[c * 8], &Wg[((long)kt * N1 + (c >> 2)) * 32 + (c & 3) * 8]);
        }
        __syncthreads();
        bf16x8 af[4], bfr[4];
#pragma unroll
        for (int r = 0; r < 4; ++r)
            af[r] = *(bf16x8*)&Al[(wr * 64 + r * 16 + lr) * 32 + kq * 8];
#pragma unroll
        for (int cg = 0; cg < 4; ++cg)
            bfr[cg] = *(bf16x8*)&Bl[(wc * 64 + cg * 16 + lr) * 32 + kq * 8];
#pragma unroll
        for (int r = 0; r < 4; ++r)
#pragma unroll
            for (int cg = 0; cg < 4; ++cg)
                acc[r][cg] = __builtin_amdgcn_mfma_f32_16x16x32_bf16(af[r], bfr[cg], acc[r][cg], 0, 0, 0);
        __syncthreads();
    }

    float ls[4] = {0.f, 0.f, 0.f, 0.f}, ls2[4] = {0.f, 0.f, 0.f, 0.f};
#pragma unroll
    for (int r = 0; r < 4; ++r) {
#pragma unroll
        for (int cg = 0; cg < 4; ++cg) {
            int kcol = (n0 + wc * 64 + cg * 16) >> 4;
#pragma unroll
            for (int j = 0; j < 4; ++j) {
                int lrow = wr * 64 + r * 16 + kq * 4 + j;
                float v = acc[r][cg][j] * Tl[lrow * 16 + lr];
                v += __shfl_xor(v, 8, 16);
                v += __shfl_xor(v, 4, 16);
                v += __shfl_xor(v, 2, 16);
                v += __shfl_xor(v, 1, 16);
                if (lr == 0) {
                    TH[(b0 + lrow) * DEEP_ + kcol] = v;
                    ls[cg] += v; ls2[cg] += v * v;
                }
            }
        }
    }
    if (lr == 0) {
#pragma unroll
        for (int cg = 0; cg < 4; ++cg) {
            atomicAdd(&sst[0][wc * 4 + cg], ls[cg]);
            atomicAdd(&sst[1][wc * 4 + cg], ls2[cg]);
        }
    }
    __syncthreads();
    if (tid < 8) {
        atomicAdd(&ACC[(n0 >> 4) + tid], sst[0][tid]);
        atomicAdd(&ACC[800 + (n0 >> 4) + tid], sst[1][tid]);
    }
}

// MFMA GEMM 2: emb_pre = fm2_bf16 @ WE; fused BN col stats
__global__ __launch_bounds__(256) void kegemm2(const ushort* __restrict__ FMB,
                                               const ushort* __restrict__ WE,
                                               float* __restrict__ EMB,
                                               float* __restrict__ ACC) {
    __shared__ ushort Al[128 * 32];
    __shared__ ushort Bl[128 * 32];
    __shared__ float  est[2][128];
    int tid = threadIdx.x;
    int wid = tid >> 6, lane = tid & 63;
    int n0 = blockIdx.x * 128;
    int b0 = blockIdx.y * 128;
    int wr = wid >> 1, wc = wid & 1;
    est[0][tid & 127] = 0.f;  // tid 0..127 row0, 128..255 row1
    est[1][tid & 127] = 0.f;

    f32x4 acc[4][4] = {};
    const ushort* Ag = FMB + (long)b0 * KEP;
    const ushort* Wg = WE + (long)n0 * 32;
    int kq = lane >> 4;
    int lr = lane & 15;

    for (int kt = 0; kt < NKTE; ++kt) {
        {
            int c = tid;
            async16(&Al[c * 8], &Ag[(c >> 2) * KEP + kt * 32 + (c & 3) * 8]);
            c = tid + 256;
            async16(&Al[c * 8], &Ag[(c >> 2) * KEP + kt * 32 + (c & 3) * 8]);
            c = tid;
            async16(&Bl[c * 8], &Wg[((long)kt * NEP + (c >> 2)) * 32 + (c & 3) * 8]);
            c = tid + 256;
            async16(&Bl[c * 8], &Wg[((long)kt * NEP + (c >> 2)) * 32 + (c & 3) * 8]);
        }
        __syncthreads();
        bf16x8 af[4], bfr[4];
#pragma unroll
        for (int r = 0; r < 4; ++r)
            af[r] = *(bf16x8*)&Al[(wr * 64 + r * 16 + lr) * 32 + kq * 8];
#pragma unroll
        for (int cg = 0; cg < 4; ++cg)
            bfr[cg] = *(bf16x8*)&Bl[(wc * 64 + cg * 16 + lr) * 32 + kq * 8];
#pragma unroll
        for (int r = 0; r < 4; ++r)
#pragma unroll
            for (int cg = 0; cg < 4; ++cg)
                acc[r][cg] = __builtin_amdgcn_mfma_f32_16x16x32_bf16(af[r], bfr[cg], acc[r][cg], 0, 0, 0);
        __syncthreads();
    }

#pragma unroll
    for (int cg = 0; cg < 4; ++cg) {
        int col = n0 + wc * 64 + cg * 16 + lr;
        float ls = 0.f, ls2 = 0.f;
#pragma unroll
        for (int r = 0; r < 4; ++r) {
#pragma unroll
            for (int j = 0; j < 4; ++j) {
                int rowi = b0 + wr * 64 + r * 16 + kq * 4 + j;
                float v = acc[r][cg][j];
                if (col < DEEP_) EMB[rowi * DEEP_ + col] = v;
                ls += v; ls2 += v * v;
            }
        }
        if (col < DEEP_) {
            atomicAdd(&est[0][wc * 64 + cg * 16 + lr], ls);
            atomicAdd(&est[1][wc * 64 + cg * 16 + lr], ls2);
        }
    }
    __syncthreads();
    if (tid < 128) {
        int col = n0 + tid;
        if (col < DEEP_) {
            atomicAdd(&ACC[400 + col], est[0][tid]);
            atomicAdd(&ACC[800 + 400 + col], est[1][tid]);
        }
    }
}

__global__ __launch_bounds__(256) void kfinal(const float* fig, const float* fibeta,
                                              const float* eg, const float* ebeta,
                                              const float* fcw, const float* fcb,
                                              const float* ws, float* out) {
    int b = blockIdx.x, tid = threadIdx.x;
    float part = 0.f;
    for (int c = tid; c < 800; c += 256) {
        float x, g, be;
        if (c < DEEP_) { x = ws[OFF_TH + b * DEEP_ + c]; g = fig[c]; be = fibeta[c]; }
        else { int cc = c - DEEP_; x = ws[OFF_EMB + b * DEEP_ + cc]; g = eg[cc]; be = ebeta[cc]; }
        float sm = ws[OFF_ACC + c], sq = ws[OFF_ACC + 800 + c];
        float mean = sm * (1.f / BATCH);
        float var = sq * (1.f / BATCH) - mean * mean;
        float rstd = rsqrtf(var + EPS_);
        float v = fmaxf(g * (x - mean) * rstd + be, 0.f);
        part += v * fcw[c];
    }
    __shared__ float red[4];
#pragma unroll
    for (int off = 32; off > 0; off >>= 1) part += __shfl_down(part, off, 64);
    if ((tid & 63) == 0) red[tid >> 6] = part;
    __syncthreads();
    if (tid == 0) {
        float tot = red[0] + red[1] + red[2] + red[3] + fcb[0];
        out[b] = 1.f / (1.f + expf(-tot));
    }
}

extern "C" void kernel_launch(void* const* d_in, const int* in_sizes, int n_in,
                              void* d_out, int out_size, void* d_ws, size_t ws_size,
                              hipStream_t stream) {
    const int*   xi    = (const int*)d_in[0];
    const float* xv    = (const float*)d_in[1];
    const float* emb   = (const float*)d_in[2];
    const float* T3    = (const float*)d_in[3];
    const float* T2    = (const float*)d_in[4];
    const float* gc    = (const float*)d_in[5];
    const float* fi_w  = (const float*)d_in[6];
    const float* fig   = (const float*)d_in[8];
    const float* fibt  = (const float*)d_in[9];
    const float* emb_w = (const float*)d_in[10];
    const float* eg    = (const float*)d_in[12];
    const float* ebt   = (const float*)d_in[13];
    const float* fcw   = (const float*)d_in[14];
    const float* fcb   = (const float*)d_in[15];
    float* ws = (float*)d_ws;
    ushort* Abf = (ushort*)(ws + OFF_ABF);
    ushort* W2  = (ushort*)(ws + OFF_W2);
    ushort* WE  = (ushort*)(ws + OFF_WE);
    ushort* FMB = (ushort*)(ws + OFF_FMB);
    float* out = (float*)d_out;

    hipLaunchKernelGGL(kprep, dim3(1), dim3(256), 0, stream, T3, T2, ws);
    hipMemsetAsync(ws + OFF_ACC, 0, 1600 * sizeof(float), stream);
    hipLaunchKernelGGL(kwr2, dim3(NKT * N1 * 4 / 256), dim3(256), 0, stream, fi_w, W2);
    hipLaunchKernelGGL(kwe, dim3(NKTE * NEP * 4 / 256), dim3(256), 0, stream, emb_w, WE);
    hipLaunchKernelGGL(kfeat, dim3(BATCH), dim3(256), 0, stream, xi, xv, emb, gc, ws, Abf, FMB);
    hipLaunchKernelGGL(kgemm2, dim3(N1 / 128, BATCH / 128), dim3(256), 0, stream,
                       Abf, W2, ws + OFF_T, ws + OFF_TH, ws + OFF_ACC);
    hipLaunchKernelGGL(kegemm2, dim3(NEP / 128, BATCH / 128), dim3(256), 0, stream,
                       FMB, WE, ws + OFF_EMB, ws + OFF_ACC);
    hipLaunchKernelGGL(kfinal, dim3(BATCH), dim3(256), 0, stream,
                       fig, fibt, eg, ebt, fcw, fcb, ws, out);
}

// Round 4
// 149.264 us; speedup vs baseline: 6.2885x; 1.1438x over previous
//
#include <hip/hip_runtime.h>
#include <hip/hip_bf16.h>

#define BATCH 4096
#define FIELDS_ 39
#define NUMF 13
#define CATF 26
#define DD 16
#define MM 16
#define VV 100000
#define DEEP_ 400
#define QQ 741
#define QPAD 768
#define KE 624      // FIELDS*D
#define KEP 640     // padded K for emb branch
#define NEP 512     // padded N for emb branch
#define N1 6400     // DEEP*M (n = kcol*16 + m)
#define NKT 24      // QPAD/32
#define NKTE 20     // KEP/32
#define EPS_ 1e-5f

// workspace layout (float offsets)
#define OFF_ABF 0                            // ushort A[b][q] stride QPAD
#define OFF_T   (BATCH*QPAD/2)               // f32 t[b][m]
#define OFF_W2  (OFF_T + BATCH*MM)           // ushort W2[kt][n][kk]
#define OFF_WE  (OFF_W2 + NKT*N1*16)         // ushort WE[kt][n][kk]
#define OFF_FMB (OFF_WE + NKTE*NEP*16)       // ushort fm2[b][k] stride KEP
#define OFF_TH  (OFF_FMB + BATCH*KEP/2)      // f32 th_pre[b][400]
#define OFF_EMB (OFF_TH + BATCH*DEEP_)       // f32 emb_pre[b][400]
#define OFF_ACC (OFF_EMB + BATCH*DEEP_)      // 800 sums + 800 sumsq
#define OFF_T2S (OFF_ACC + 1600)
#define OFF_T3D (OFF_T2S + 16)
#define OFF_QIJ (OFF_T3D + 256)              // int table q -> (i<<8|j)

typedef __attribute__((ext_vector_type(8))) short bf16x8;
typedef __attribute__((ext_vector_type(4))) float f32x4;

__device__ __forceinline__ ushort f2bf(float v) {
    union { float f; unsigned u; } x; x.f = v;
    unsigned r = x.u + 0x7fff + ((x.u >> 16) & 1);
    return (ushort)(r >> 16);
}
__device__ __forceinline__ void async16(void* lds, const void* g) {
    __builtin_amdgcn_global_load_lds(
        (const __attribute__((address_space(1))) unsigned int*)g,
        (__attribute__((address_space(3))) unsigned int*)lds,
        16, 0, 0);
}

__global__ void kprep(const float* T3, const float* T2, float* ws) {
    int tid = threadIdx.x;
    if (tid < MM) {
        float s = 0.f;
        for (int j = 0; j < DD * DD; ++j) s += T2[tid * DD * DD + j];
        ws[OFF_T2S + tid] = s;
    }
    if (tid < DD * MM) {
        int d = tid >> 4, m = tid & 15;
        ws[OFF_T3D + tid] = T3[(d * MM + m) * DD + d];
    }
    for (int i = tid; i < 1600; i += 256) ws[OFF_ACC + i] = 0.f;
    int* qij = (int*)(ws + OFF_QIJ);
    for (int q = tid; q < QPAD; q += 256) {
        int v = 0;
        if (q < QQ) {
            int i = 0, qq = q, cnt = FIELDS_ - 1;
            while (qq >= cnt) { qq -= cnt; ++i; cnt = FIELDS_ - 1 - i; }
            v = (i << 8) | (i + 1 + qq);
        }
        qij[q] = v;
    }
}

// fi_w -> W2[kt][n][kk] bf16: coalesced float4 reads (4 consecutive kcol),
// 4 scattered 2B stores (L2 write-combines full lines).
__global__ void kwr2(const float* __restrict__ fi_w, ushort* __restrict__ W2) {
    int idx = blockIdx.x * 256 + threadIdx.x;   // q*2048 + m*128 + s
    int q = idx >> 11;                          // 0..767
    int m = (idx >> 7) & 15;
    int s = idx & 127;                          // kcol quad slot; s<100 active
    if (s >= 100) return;
    int kt = q >> 5, kk = q & 31;
    float4 v = make_float4(0.f, 0.f, 0.f, 0.f);
    if (q < QQ) v = *(const float4*)&fi_w[(q * MM + m) * DEEP_ + s * 4];
    const float* vp = (const float*)&v;
#pragma unroll
    for (int i = 0; i < 4; ++i) {
        int n = (s * 4 + i) * 16 + m;
        W2[((long)(kt * N1 + n)) * 32 + kk] = f2bf(vp[i]);
    }
}

// emb_w -> WE[kt][n][kk] bf16 (K 624->640 pad, N 400->512 pad)
__global__ void kwe(const float* __restrict__ emb_w, ushort* __restrict__ WE) {
    int idx = blockIdx.x * 256 + threadIdx.x;   // k*128 + s
    int k = idx >> 7;                           // 0..639
    int s = idx & 127;                          // n quad; s<100 reads, s<128 zero-fill
    int kt = k >> 5, kk = k & 31;
    float4 v = make_float4(0.f, 0.f, 0.f, 0.f);
    if (k < KE && s < 100) v = *(const float4*)&emb_w[k * DEEP_ + s * 4];
    const float* vp = (const float*)&v;
#pragma unroll
    for (int i = 0; i < 4; ++i) {
        int n = s * 4 + i;
        if (n < NEP) WE[((long)(kt * NEP + n)) * 32 + kk] = f2bf(vp[i]);
    }
}

// fused: gather fm2 -> FMB bf16, FM-identity h, ga, softmax*t2sum -> T, pair dots -> Abf
__global__ __launch_bounds__(256) void kfeat(const int* __restrict__ xi,
                                             const float* __restrict__ xv,
                                             const float* __restrict__ emb,
                                             const float* __restrict__ gc,
                                             float* __restrict__ ws,
                                             ushort* __restrict__ Abf,
                                             ushort* __restrict__ FMB) {
    __shared__ float row[KE];
    __shared__ float hsh[DD];
    __shared__ float gash[MM];
    int b = blockIdx.x, tid = threadIdx.x;
    for (int e = tid; e < KE; e += 256) {
        int f = e >> 4, d = e & 15;
        float v;
        if (f < NUMF) {
            v = xv[b * NUMF + f] * emb[(long)f * VV * DD + d];
        } else {
            int c = f - NUMF;
            int idxv = xi[b * CATF + c];
            v = emb[((long)(NUMF + c) * VV + idxv) * DD + d];
        }
        row[e] = v;
    }
    __syncthreads();
    for (int e = tid; e < KEP; e += 256)
        FMB[(long)b * KEP + e] = (e < KE) ? f2bf(row[e]) : (ushort)0;
    if (tid < DD) {
        float s = 0.f, s2 = 0.f;
        for (int f = 0; f < FIELDS_; ++f) { float v = row[f * DD + tid]; s += v; s2 += v * v; }
        hsh[tid] = 0.5f * (s * s - s2);
    }
    __syncthreads();
    if (tid < MM) {
        float g = 0.f;
        for (int d = 0; d < DD; ++d) g += hsh[d] * ws[OFF_T3D + d * MM + tid];
        gash[tid] = g;
    }
    __syncthreads();
    if (tid < MM) {
        float mx = -1e30f;
        for (int m = 0; m < MM; ++m) mx = fmaxf(mx, gash[m]);
        float se = 0.f;
        for (int m = 0; m < MM; ++m) se += expf(gash[m] - mx);
        ws[OFF_T + b * MM + tid] = expf(gash[tid] - mx) / se * ws[OFF_T2S + tid];
    }
    const int* qij = (const int*)(ws + OFF_QIJ);
    for (int q = tid; q < QPAD; q += 256) {
        float av = 0.f;
        if (q < QQ) {
            int ij = qij[q];
            int i = ij >> 8, j = ij & 255;
            float dot = 0.f;
#pragma unroll
            for (int d = 0; d < DD; ++d) dot += row[i * DD + d] * row[j * DD + d];
            av = dot * gc[q];
        }
        Abf[(long)b * QPAD + q] = f2bf(av);
    }
}

// MFMA GEMM 1 (operand-swapped): C'[n,b] = mfma(W-frag, A-frag).
// Epilogue: th[b,kcol] = dot4(acc, t4) reduced over kq via 2 shfl_xor.
__global__ __launch_bounds__(256) void kgemm2(const ushort* __restrict__ Abf,
                                              const ushort* __restrict__ W2,
                                              const float* __restrict__ Tmat,
                                              float* __restrict__ TH,
                                              float* __restrict__ ACC) {
    __shared__ ushort Al[128 * 32];   // A rows (b)
    __shared__ ushort Bl[128 * 32];   // W cols (n)
    __shared__ float  Tl[128 * 16];
    __shared__ float  sst[2][8];
    int tid = threadIdx.x;
    int wid = tid >> 6, lane = tid & 63;
    int wg = blockIdx.x;                       // 1600 blocks, XCD swizzle
    int swz = (wg & 7) * 200 + (wg >> 3);
    int bx = swz >> 5;                         // 0..49
    int by = swz & 31;                         // 0..31
    int n0 = bx * 128;
    int b0 = by * 128;
    int wr = wid >> 1, wc = wid & 1;
    if (tid < 16) sst[tid >> 3][tid & 7] = 0.f;

    for (int i = tid; i < 128 * 16 / 4; i += 256)
        *(float4*)&Tl[i * 4] = *(const float4*)&Tmat[b0 * 16 + i * 4];

    f32x4 acc[4][4] = {};
    const ushort* Ag = Abf + (long)b0 * QPAD;
    const ushort* Wg = W2 + (long)n0 * 32;
    int kq = lane >> 4;
    int lr = lane & 15;

    for (int kt = 0; kt < NKT; ++kt) {
        {
            int c = tid;
            async16(&Al[c * 8], &Ag[(c >> 2) * QPAD + kt * 32 + (c & 3) * 8]);
            c = tid + 256;
            async16(&Al[c * 8], &Ag[(c >> 2) * QPAD + kt * 32 + (c & 3) * 8]);
            c = tid;
            async16(&Bl[c * 8], &Wg[((long)kt * N1 + (c >> 2)) * 32 + (c & 3) * 8]);
            c = tid + 256;
            async16(&Bl[c * 8], &Wg[((long)kt * N1 + (c >> 2)) * 32 + (c & 3) * 8]);
        }
        __syncthreads();
        bf16x8 wf[4], af[4];
#pragma unroll
        for (int r = 0; r < 4; ++r)                      // n sub-tiles
            wf[r] = *(bf16x8*)&Bl[(wr * 64 + r * 16 + lr) * 32 + kq * 8];
#pragma unroll
        for (int cg = 0; cg < 4; ++cg)                   // b sub-tiles
            af[cg] = *(bf16x8*)&Al[(wc * 64 + cg * 16 + lr) * 32 + kq * 8];
#pragma unroll
        for (int r = 0; r < 4; ++r)
#pragma unroll
            for (int cg = 0; cg < 4; ++cg)
                acc[r][cg] = __builtin_amdgcn_mfma_f32_16x16x32_bf16(wf[r], af[cg], acc[r][cg], 0, 0, 0);
        __syncthreads();
    }

    // acc[r][cg]: C'[n = n0+wr*64+r*16+kq*4+j, b = b0+wc*64+cg*16+lr]
    float ls[4] = {0.f, 0.f, 0.f, 0.f}, ls2[4] = {0.f, 0.f, 0.f, 0.f};
#pragma unroll
    for (int cg = 0; cg < 4; ++cg) {
        int bloc = wc * 64 + cg * 16 + lr;
        float4 t4 = *(const float4*)&Tl[bloc * 16 + kq * 4];
#pragma unroll
        for (int r = 0; r < 4; ++r) {
            float s = acc[r][cg][0] * t4.x + acc[r][cg][1] * t4.y +
                      acc[r][cg][2] * t4.z + acc[r][cg][3] * t4.w;
            s += __shfl_xor(s, 16);
            s += __shfl_xor(s, 32);
            ls[r] += s; ls2[r] += s * s;
            if (lane < 16)
                TH[(b0 + bloc) * DEEP_ + ((n0 + wr * 64 + r * 16) >> 4)] = s;
        }
    }
#pragma unroll
    for (int r = 0; r < 4; ++r) {
        float a = ls[r], b2 = ls2[r];
        a += __shfl_xor(a, 8, 16); b2 += __shfl_xor(b2, 8, 16);
        a += __shfl_xor(a, 4, 16); b2 += __shfl_xor(b2, 4, 16);
        a += __shfl_xor(a, 2, 16); b2 += __shfl_xor(b2, 2, 16);
        a += __shfl_xor(a, 1, 16); b2 += __shfl_xor(b2, 1, 16);
        if (lane == 0) {
            atomicAdd(&sst[0][wr * 4 + r], a);
            atomicAdd(&sst[1][wr * 4 + r], b2);
        }
    }
    __syncthreads();
    if (tid < 8) {
        atomicAdd(&ACC[(n0 >> 4) + tid], sst[0][tid]);
        atomicAdd(&ACC[800 + (n0 >> 4) + tid], sst[1][tid]);
    }
}

// MFMA GEMM 2: emb_pre = fm2_bf16 @ WE; fused BN col stats
__global__ __launch_bounds__(256) void kegemm2(const ushort* __restrict__ FMB,
                                               const ushort* __restrict__ WE,
                                               float* __restrict__ EMB,
                                               float* __restrict__ ACC) {
    __shared__ ushort Al[128 * 32];
    __shared__ ushort Bl[128 * 32];
    __shared__ float  est[2][128];
    int tid = threadIdx.x;
    int wid = tid >> 6, lane = tid & 63;
    int wg = blockIdx.x;                       // 128 blocks, XCD swizzle
    int swz = (wg & 7) * 16 + (wg >> 3);
    int bx = swz >> 5;                         // 0..3
    int by = swz & 31;
    int n0 = bx * 128;
    int b0 = by * 128;
    int wr = wid >> 1, wc = wid & 1;
    est[0][tid & 127] = 0.f;
    est[1][tid & 127] = 0.f;

    f32x4 acc[4][4] = {};
    const ushort* Ag = FMB + (long)b0 * KEP;
    const ushort* Wg = WE + (long)n0 * 32;
    int kq = lane >> 4;
    int lr = lane & 15;

    for (int kt = 0; kt < NKTE; ++kt) {
        {
            int c = tid;
            async16(&Al[c * 8], &Ag[(c >> 2) * KEP + kt * 32 + (c & 3) * 8]);
            c = tid + 256;
            async16(&Al[c * 8], &Ag[(c >> 2) * KEP + kt * 32 + (c & 3) * 8]);
            c = tid;
            async16(&Bl[c * 8], &Wg[((long)kt * NEP + (c >> 2)) * 32 + (c & 3) * 8]);
            c = tid + 256;
            async16(&Bl[c * 8], &Wg[((long)kt * NEP + (c >> 2)) * 32 + (c & 3) * 8]);
        }
        __syncthreads();
        bf16x8 af[4], bfr[4];
#pragma unroll
        for (int r = 0; r < 4; ++r)
            af[r] = *(bf16x8*)&Al[(wr * 64 + r * 16 + lr) * 32 + kq * 8];
#pragma unroll
        for (int cg = 0; cg < 4; ++cg)
            bfr[cg] = *(bf16x8*)&Bl[(wc * 64 + cg * 16 + lr) * 32 + kq * 8];
#pragma unroll
        for (int r = 0; r < 4; ++r)
#pragma unroll
            for (int cg = 0; cg < 4; ++cg)
                acc[r][cg] = __builtin_amdgcn_mfma_f32_16x16x32_bf16(af[r], bfr[cg], acc[r][cg], 0, 0, 0);
        __syncthreads();
    }

#pragma unroll
    for (int cg = 0; cg < 4; ++cg) {
        int col = n0 + wc * 64 + cg * 16 + lr;
        float ls = 0.f, ls2 = 0.f;
#pragma unroll
        for (int r = 0; r < 4; ++r) {
#pragma unroll
            for (int j = 0; j < 4; ++j) {
                int rowi = b0 + wr * 64 + r * 16 + kq * 4 + j;
                float v = acc[r][cg][j];
                if (col < DEEP_) EMB[rowi * DEEP_ + col] = v;
                ls += v; ls2 += v * v;
            }
        }
        if (col < DEEP_) {
            atomicAdd(&est[0][wc * 64 + cg * 16 + lr], ls);
            atomicAdd(&est[1][wc * 64 + cg * 16 + lr], ls2);
        }
    }
    __syncthreads();
    if (tid < 128) {
        int col = n0 + tid;
        if (col < DEEP_) {
            atomicAdd(&ACC[400 + col], est[0][tid]);
            atomicAdd(&ACC[800 + 400 + col], est[1][tid]);
        }
    }
}

__global__ __launch_bounds__(256) void kfinal(const float* fig, const float* fibeta,
                                              const float* eg, const float* ebeta,
                                              const float* fcw, const float* fcb,
                                              const float* ws, float* out) {
    int b = blockIdx.x, tid = threadIdx.x;
    float part = 0.f;
    for (int c = tid; c < 800; c += 256) {
        float x, g, be;
        if (c < DEEP_) { x = ws[OFF_TH + b * DEEP_ + c]; g = fig[c]; be = fibeta[c]; }
        else { int cc = c - DEEP_; x = ws[OFF_EMB + b * DEEP_ + cc]; g = eg[cc]; be = ebeta[cc]; }
        float sm = ws[OFF_ACC + c], sq = ws[OFF_ACC + 800 + c];
        float mean = sm * (1.f / BATCH);
        float var = sq * (1.f / BATCH) - mean * mean;
        float rstd = rsqrtf(var + EPS_);
        float v = fmaxf(g * (x - mean) * rstd + be, 0.f);
        part += v * fcw[c];
    }
    __shared__ float red[4];
#pragma unroll
    for (int off = 32; off > 0; off >>= 1) part += __shfl_down(part, off, 64);
    if ((tid & 63) == 0) red[tid >> 6] = part;
    __syncthreads();
    if (tid == 0) {
        float tot = red[0] + red[1] + red[2] + red[3] + fcb[0];
        out[b] = 1.f / (1.f + expf(-tot));
    }
}

extern "C" void kernel_launch(void* const* d_in, const int* in_sizes, int n_in,
                              void* d_out, int out_size, void* d_ws, size_t ws_size,
                              hipStream_t stream) {
    const int*   xi    = (const int*)d_in[0];
    const float* xv    = (const float*)d_in[1];
    const float* emb   = (const float*)d_in[2];
    const float* T3    = (const float*)d_in[3];
    const float* T2    = (const float*)d_in[4];
    const float* gc    = (const float*)d_in[5];
    const float* fi_w  = (const float*)d_in[6];
    const float* fig   = (const float*)d_in[8];
    const float* fibt  = (const float*)d_in[9];
    const float* emb_w = (const float*)d_in[10];
    const float* eg    = (const float*)d_in[12];
    const float* ebt   = (const float*)d_in[13];
    const float* fcw   = (const float*)d_in[14];
    const float* fcb   = (const float*)d_in[15];
    float* ws = (float*)d_ws;
    ushort* Abf = (ushort*)(ws + OFF_ABF);
    ushort* W2  = (ushort*)(ws + OFF_W2);
    ushort* WE  = (ushort*)(ws + OFF_WE);
    ushort* FMB = (ushort*)(ws + OFF_FMB);
    float* out = (float*)d_out;

    hipLaunchKernelGGL(kprep, dim3(1), dim3(256), 0, stream, T3, T2, ws);
    hipLaunchKernelGGL(kwr2, dim3(QPAD * 2048 / 256), dim3(256), 0, stream, fi_w, W2);
    hipLaunchKernelGGL(kwe, dim3(KEP * 128 / 256), dim3(256), 0, stream, emb_w, WE);
    hipLaunchKernelGGL(kfeat, dim3(BATCH), dim3(256), 0, stream, xi, xv, emb, gc, ws, Abf, FMB);
    hipLaunchKernelGGL(kgemm2, dim3(1600), dim3(256), 0, stream,
                       Abf, W2, ws + OFF_T, ws + OFF_TH, ws + OFF_ACC);
    hipLaunchKernelGGL(kegemm2, dim3(128), dim3(256), 0, stream,
                       FMB, WE, ws + OFF_EMB, ws + OFF_ACC);
    hipLaunchKernelGGL(kfinal, dim3(BATCH), dim3(256), 0, stream,
                       fig, fibt, eg, ebt, fcw, fcb, ws, out);
}

// Round 5
// 137.244 us; speedup vs baseline: 6.8393x; 1.0876x over previous
//
#include <hip/hip_runtime.h>
#include <hip/hip_bf16.h>

#define BATCH 4096
#define FIELDS_ 39
#define NUMF 13
#define CATF 26
#define DD 16
#define MM 16
#define VV 100000
#define DEEP_ 400
#define QQ 741
#define QPAD 768
#define KE 624      // FIELDS*D
#define KEP 640     // padded K for emb branch
#define NEP 512     // padded N for emb branch
#define N1 6400     // DEEP*M (n = kcol*16 + m)
#define NKTE 20     // KEP/32
#define NT_ 24      // QPAD/32 K-tiles for main GEMM
#define EPS_ 1e-5f

// workspace layout (float offsets)
#define OFF_ABF 0                            // ushort A[b][768] row-major
#define OFF_T   (BATCH*QPAD/2)               // f32 t[b][m]
#define OFF_W2  (OFF_T + BATCH*MM)           // ushort W2[n][768] row-major
#define OFF_WE  (OFF_W2 + N1*QPAD/2)         // ushort WE[kt][n][kk] (kegemm2 layout)
#define OFF_FMB (OFF_WE + NKTE*NEP*16)       // ushort fm2[b][k] stride KEP
#define OFF_TH  (OFF_FMB + BATCH*KEP/2)      // f32 th_pre[b][400]
#define OFF_EMB (OFF_TH + BATCH*DEEP_)       // f32 emb_pre[b][400]
#define OFF_ACC (OFF_EMB + BATCH*DEEP_)      // 800 sums + 800 sumsq
#define OFF_T2S (OFF_ACC + 1600)
#define OFF_T3D (OFF_T2S + 16)
#define OFF_QIJ (OFF_T3D + 256)              // int table q -> (i<<8|j)

typedef __attribute__((ext_vector_type(8))) short bf16x8;
typedef __attribute__((ext_vector_type(4))) float f32x4;

__device__ __forceinline__ ushort f2bf(float v) {
    union { float f; unsigned u; } x; x.f = v;
    unsigned r = x.u + 0x7fff + ((x.u >> 16) & 1);
    return (ushort)(r >> 16);
}
__device__ __forceinline__ unsigned pack2(float a, float b) {
    return (unsigned)f2bf(a) | ((unsigned)f2bf(b) << 16);
}
__device__ __forceinline__ void async16(void* lds, const void* g) {
    __builtin_amdgcn_global_load_lds(
        (const __attribute__((address_space(1))) unsigned int*)g,
        (__attribute__((address_space(3))) unsigned int*)lds,
        16, 0, 0);
}

__global__ void kprep(const float* T3, const float* T2, float* ws) {
    int tid = threadIdx.x;
    if (tid < MM) {
        float s = 0.f;
        for (int j = 0; j < DD * DD; ++j) s += T2[tid * DD * DD + j];
        ws[OFF_T2S + tid] = s;
    }
    if (tid < DD * MM) {
        int d = tid >> 4, m = tid & 15;
        ws[OFF_T3D + tid] = T3[(d * MM + m) * DD + d];
    }
    for (int i = tid; i < 1600; i += 256) ws[OFF_ACC + i] = 0.f;
    int* qij = (int*)(ws + OFF_QIJ);
    for (int q = tid; q < QPAD; q += 256) {
        int v = 0;
        if (q < QQ) {
            int i = 0, qq = q, cnt = FIELDS_ - 1;
            while (qq >= cnt) { qq -= cnt; ++i; cnt = FIELDS_ - 1 - i; }
            v = (i << 8) | (i + 1 + qq);
        }
        qij[q] = v;
    }
}

// fi_w -> W2[n][768] via LDS transpose. Block = (kt, m): reads 32 q-rows of 400
// f32 coalesced, writes 400 n-rows x 32 q as full 64B lines.
__global__ __launch_bounds__(256) void kwr2(const float* __restrict__ fi_w,
                                            ushort* __restrict__ W2) {
    __shared__ float tile[32][401];   // pad 401: transpose reads conflict-free
    int kt = blockIdx.x >> 4, m = blockIdx.x & 15;
    int tid = threadIdx.x;
    for (int i = tid; i < 32 * 100; i += 256) {
        int ql = i / 100, c4 = i - ql * 100;
        int q = kt * 32 + ql;
        float4 v = make_float4(0.f, 0.f, 0.f, 0.f);
        if (q < QQ) v = *(const float4*)&fi_w[(q * MM + m) * DEEP_ + c4 * 4];
        tile[ql][c4 * 4 + 0] = v.x; tile[ql][c4 * 4 + 1] = v.y;
        tile[ql][c4 * 4 + 2] = v.z; tile[ql][c4 * 4 + 3] = v.w;
    }
    __syncthreads();
    for (int i = tid; i < 400 * 4; i += 256) {
        int kcol = i >> 2, cq = i & 3;
        unsigned r[4];
#pragma unroll
        for (int j = 0; j < 4; ++j) {
            float a = tile[cq * 8 + 2 * j][kcol];
            float b = tile[cq * 8 + 2 * j + 1][kcol];
            r[j] = pack2(a, b);
        }
        *(uint4*)&W2[(long)(kcol * 16 + m) * QPAD + kt * 32 + cq * 8] =
            make_uint4(r[0], r[1], r[2], r[3]);
    }
}

// emb_w -> WE[kt][n][kk] bf16 (K 624->640 pad, N 400->512 pad)
__global__ void kwe(const float* __restrict__ emb_w, ushort* __restrict__ WE) {
    int idx = blockIdx.x * 256 + threadIdx.x;
    int k = idx >> 7;
    int s = idx & 127;
    int kt = k >> 5, kk = k & 31;
    float4 v = make_float4(0.f, 0.f, 0.f, 0.f);
    if (k < KE && s < 100) v = *(const float4*)&emb_w[k * DEEP_ + s * 4];
    const float* vp = (const float*)&v;
#pragma unroll
    for (int i = 0; i < 4; ++i) {
        int n = s * 4 + i;
        if (n < NEP) WE[((long)(kt * NEP + n)) * 32 + kk] = f2bf(vp[i]);
    }
}

// fused: gather fm2 -> FMB bf16, FM-identity h, ga, softmax*t2sum -> T, pair dots -> Abf
__global__ __launch_bounds__(256) void kfeat(const int* __restrict__ xi,
                                             const float* __restrict__ xv,
                                             const float* __restrict__ emb,
                                             const float* __restrict__ gc,
                                             float* __restrict__ ws,
                                             ushort* __restrict__ Abf,
                                             ushort* __restrict__ FMB) {
    __shared__ float row[KE];
    __shared__ float hsh[DD];
    __shared__ float gash[MM];
    int b = blockIdx.x, tid = threadIdx.x;
    for (int e = tid; e < KE; e += 256) {
        int f = e >> 4, d = e & 15;
        float v;
        if (f < NUMF) {
            v = xv[b * NUMF + f] * emb[(long)f * VV * DD + d];
        } else {
            int c = f - NUMF;
            int idxv = xi[b * CATF + c];
            v = emb[((long)(NUMF + c) * VV + idxv) * DD + d];
        }
        row[e] = v;
    }
    __syncthreads();
    for (int e = tid; e < KEP; e += 256)
        FMB[(long)b * KEP + e] = (e < KE) ? f2bf(row[e]) : (ushort)0;
    if (tid < DD) {
        float s = 0.f, s2 = 0.f;
        for (int f = 0; f < FIELDS_; ++f) { float v = row[f * DD + tid]; s += v; s2 += v * v; }
        hsh[tid] = 0.5f * (s * s - s2);
    }
    __syncthreads();
    if (tid < MM) {
        float g = 0.f;
        for (int d = 0; d < DD; ++d) g += hsh[d] * ws[OFF_T3D + d * MM + tid];
        gash[tid] = g;
    }
    __syncthreads();
    if (tid < MM) {
        float mx = -1e30f;
        for (int m = 0; m < MM; ++m) mx = fmaxf(mx, gash[m]);
        float se = 0.f;
        for (int m = 0; m < MM; ++m) se += expf(gash[m] - mx);
        ws[OFF_T + b * MM + tid] = expf(gash[tid] - mx) / se * ws[OFF_T2S + tid];
    }
    const int* qij = (const int*)(ws + OFF_QIJ);
    for (int q = tid; q < QPAD; q += 256) {
        float av = 0.f;
        if (q < QQ) {
            int ij = qij[q];
            int i = ij >> 8, j = ij & 255;
            float dot = 0.f;
#pragma unroll
            for (int d = 0; d < DD; ++d) dot += row[i * DD + d] * row[j * DD + d];
            av = dot * gc[q];
        }
        Abf[(long)b * QPAD + q] = f2bf(av);
    }
}

__device__ __forceinline__ void mfma16(const bf16x8* w, const bf16x8* a, f32x4 (*acc)[4]) {
#pragma unroll
    for (int r = 0; r < 4; ++r)
#pragma unroll
        for (int c = 0; c < 4; ++c)
            acc[r][c] = __builtin_amdgcn_mfma_f32_16x16x32_bf16(w[r], a[c], acc[r][c], 0, 0, 0);
}

__device__ __forceinline__ void loadfrags(const ushort* base, int wn, int wb,
                                          int kq, int lr, bf16x8* w, bf16x8* a) {
    const ushort* bB = base + 128 * 32;
    int sw = (kq ^ ((lr >> 1) & 3)) * 8;
#pragma unroll
    for (int r = 0; r < 4; ++r) {
        int row = wn * 64 + r * 16 + lr;
        w[r] = *(const bf16x8*)&bB[row * 32 + sw];
    }
#pragma unroll
    for (int c = 0; c < 4; ++c) {
        int row = wb * 64 + c * 16 + lr;
        a[c] = *(const bf16x8*)&base[row * 32 + sw];
    }
}

// Main fused GEMM: counted-vmcnt 3-slot pipeline, 1 barrier/K-step, raw s_barrier.
// Tile 128(b) x 256(n), BK=32, 512 threads = 8 waves (2b x 4n), 64x64 per wave.
__global__ __launch_bounds__(512) void kgemm3(const ushort* __restrict__ Abf,
                                              const ushort* __restrict__ W2,
                                              const float* __restrict__ Tmat,
                                              float* __restrict__ TH,
                                              float* __restrict__ ACC) {
    __shared__ ushort LDSBUF[3][384 * 32];   // per slot: A[128][32] then B[256][32]
    __shared__ float Tl[128 * 16];
    __shared__ float sst[2][16];
    int tid = threadIdx.x;
    int wid = tid >> 6, lane = tid & 63;
    int wb = wid >> 2, wn = wid & 3;
    int kq = lane >> 4, lr = lane & 15;
    int wg = blockIdx.x;                      // 800 blocks
    int s = (wg & 7) * 100 + (wg >> 3);       // XCD swizzle (800 % 8 == 0)
    int bx = s >> 5;                          // 0..24 n-panel
    int by = s & 31;                          // 0..31 b-panel
    int n0 = bx * 256, b0 = by * 128;

    if (tid < 32) sst[tid >> 4][tid & 15] = 0.f;
    *(float4*)&Tl[tid * 4] = *(const float4*)&Tmat[b0 * 16 + tid * 4];

    // staging source pointers (inverse-swizzled global, linear LDS dest)
    int arow = tid >> 2, ac = tid & 3;
    int csw = (ac ^ ((arow >> 1) & 3)) * 8;
    const ushort* As  = Abf + (long)(b0 + arow) * QPAD + csw;
    const ushort* Bs0 = W2 + (long)(n0 + arow) * QPAD + csw;
    const ushort* Bs1 = W2 + (long)(n0 + 128 + arow) * QPAD + csw;

#define STAGE(SL, KT) { \
    ushort* base_ = &LDSBUF[SL][0]; \
    async16(base_ + tid * 8, As + (KT) * 32); \
    async16(base_ + 4096 + tid * 8, Bs0 + (KT) * 32); \
    async16(base_ + 8192 + tid * 8, Bs1 + (KT) * 32); \
}

    f32x4 acc[4][4] = {};
    bf16x8 w0[4], a0[4], w1[4], a1[4];

    STAGE(0, 0); STAGE(1, 1); STAGE(2, 2);
    asm volatile("s_waitcnt vmcnt(6)" ::: "memory");
    __builtin_amdgcn_s_barrier();
    loadfrags(&LDSBUF[0][0], wn, wb, kq, lr, w0, a0);
    int sl = 0;

#define ITER(T, WC, AC, WN, AN) { \
    asm volatile("s_waitcnt lgkmcnt(0)"); \
    __builtin_amdgcn_sched_barrier(0); \
    __builtin_amdgcn_s_barrier(); \
    if ((T) + 3 < NT_) STAGE(sl, (T) + 3); \
    int sln_ = (sl == 2) ? 0 : sl + 1; \
    if ((T) + 1 < NT_) { \
        if ((T) + 3 < NT_)      { asm volatile("s_waitcnt vmcnt(6)" ::: "memory"); } \
        else if ((T) + 2 < NT_) { asm volatile("s_waitcnt vmcnt(3)" ::: "memory"); } \
        else                    { asm volatile("s_waitcnt vmcnt(0)" ::: "memory"); } \
        loadfrags(&LDSBUF[sln_][0], wn, wb, kq, lr, WN, AN); \
    } \
    __builtin_amdgcn_s_setprio(1); \
    mfma16(WC, AC, acc); \
    __builtin_amdgcn_s_setprio(0); \
    sl = sln_; \
}

    for (int t = 0; t < NT_; t += 2) {
        ITER(t,     w0, a0, w1, a1);
        ITER(t + 1, w1, a1, w0, a0);
    }
#undef ITER
#undef STAGE

    // epilogue: acc[r][cg][j] = C'[n = n0+wn*64+r*16+kq*4+j][b = b0+wb*64+cg*16+lr]
    float ls[4] = {0.f, 0.f, 0.f, 0.f}, ls2[4] = {0.f, 0.f, 0.f, 0.f};
#pragma unroll
    for (int cg = 0; cg < 4; ++cg) {
        int bloc = wb * 64 + cg * 16 + lr;
        float4 t4 = *(const float4*)&Tl[bloc * 16 + kq * 4];
#pragma unroll
        for (int r = 0; r < 4; ++r) {
            float v = acc[r][cg][0] * t4.x + acc[r][cg][1] * t4.y +
                      acc[r][cg][2] * t4.z + acc[r][cg][3] * t4.w;
            v += __shfl_xor(v, 16);
            v += __shfl_xor(v, 32);
            ls[r] += v; ls2[r] += v * v;
            if (lane < 16)
                TH[(b0 + bloc) * DEEP_ + (n0 >> 4) + wn * 4 + r] = v;
        }
    }
#pragma unroll
    for (int r = 0; r < 4; ++r) {
        float a = ls[r], b2 = ls2[r];
        a += __shfl_xor(a, 8, 16); b2 += __shfl_xor(b2, 8, 16);
        a += __shfl_xor(a, 4, 16); b2 += __shfl_xor(b2, 4, 16);
        a += __shfl_xor(a, 2, 16); b2 += __shfl_xor(b2, 2, 16);
        a += __shfl_xor(a, 1, 16); b2 += __shfl_xor(b2, 1, 16);
        if (lane == 0) {
            atomicAdd(&sst[0][wn * 4 + r], a);
            atomicAdd(&sst[1][wn * 4 + r], b2);
        }
    }
    __syncthreads();
    if (tid < 16) {
        atomicAdd(&ACC[(n0 >> 4) + tid], sst[0][tid]);
        atomicAdd(&ACC[800 + (n0 >> 4) + tid], sst[1][tid]);
    }
}

// emb branch GEMM (unchanged 128^2 structure): emb_pre = fm2_bf16 @ WE + BN stats
__global__ __launch_bounds__(256) void kegemm2(const ushort* __restrict__ FMB,
                                               const ushort* __restrict__ WE,
                                               float* __restrict__ EMB,
                                               float* __restrict__ ACC) {
    __shared__ ushort Al[128 * 32];
    __shared__ ushort Bl[128 * 32];
    __shared__ float  est[2][128];
    int tid = threadIdx.x;
    int wid = tid >> 6, lane = tid & 63;
    int wg = blockIdx.x;
    int swz = (wg & 7) * 16 + (wg >> 3);
    int bx = swz >> 5;
    int by = swz & 31;
    int n0 = bx * 128;
    int b0 = by * 128;
    int wr = wid >> 1, wc = wid & 1;
    est[0][tid & 127] = 0.f;
    est[1][tid & 127] = 0.f;

    f32x4 acc[4][4] = {};
    const ushort* Ag = FMB + (long)b0 * KEP;
    const ushort* Wg = WE + (long)n0 * 32;
    int kq = lane >> 4;
    int lr = lane & 15;

    for (int kt = 0; kt < NKTE; ++kt) {
        {
            int c = tid;
            async16(&Al[c * 8], &Ag[(c >> 2) * KEP + kt * 32 + (c & 3) * 8]);
            c = tid + 256;
            async16(&Al[c * 8], &Ag[(c >> 2) * KEP + kt * 32 + (c & 3) * 8]);
            c = tid;
            async16(&Bl[c * 8], &Wg[((long)kt * NEP + (c >> 2)) * 32 + (c & 3) * 8]);
            c = tid + 256;
            async16(&Bl[c * 8], &Wg[((long)kt * NEP + (c >> 2)) * 32 + (c & 3) * 8]);
        }
        __syncthreads();
        bf16x8 af[4], bfr[4];
#pragma unroll
        for (int r = 0; r < 4; ++r)
            af[r] = *(bf16x8*)&Al[(wr * 64 + r * 16 + lr) * 32 + kq * 8];
#pragma unroll
        for (int cg = 0; cg < 4; ++cg)
            bfr[cg] = *(bf16x8*)&Bl[(wc * 64 + cg * 16 + lr) * 32 + kq * 8];
#pragma unroll
        for (int r = 0; r < 4; ++r)
#pragma unroll
            for (int cg = 0; cg < 4; ++cg)
                acc[r][cg] = __builtin_amdgcn_mfma_f32_16x16x32_bf16(af[r], bfr[cg], acc[r][cg], 0, 0, 0);
        __syncthreads();
    }

#pragma unroll
    for (int cg = 0; cg < 4; ++cg) {
        int col = n0 + wc * 64 + cg * 16 + lr;
        float ls = 0.f, ls2 = 0.f;
#pragma unroll
        for (int r = 0; r < 4; ++r) {
#pragma unroll
            for (int j = 0; j < 4; ++j) {
                int rowi = b0 + wr * 64 + r * 16 + kq * 4 + j;
                float v = acc[r][cg][j];
                if (col < DEEP_) EMB[rowi * DEEP_ + col] = v;
                ls += v; ls2 += v * v;
            }
        }
        if (col < DEEP_) {
            atomicAdd(&est[0][wc * 64 + cg * 16 + lr], ls);
            atomicAdd(&est[1][wc * 64 + cg * 16 + lr], ls2);
        }
    }
    __syncthreads();
    if (tid < 128) {
        int col = n0 + tid;
        if (col < DEEP_) {
            atomicAdd(&ACC[400 + col], est[0][tid]);
            atomicAdd(&ACC[800 + 400 + col], est[1][tid]);
        }
    }
}

__global__ __launch_bounds__(256) void kfinal(const float* fig, const float* fibeta,
                                              const float* eg, const float* ebeta,
                                              const float* fcw, const float* fcb,
                                              const float* ws, float* out) {
    int b = blockIdx.x, tid = threadIdx.x;
    float part = 0.f;
    for (int c = tid; c < 800; c += 256) {
        float x, g, be;
        if (c < DEEP_) { x = ws[OFF_TH + b * DEEP_ + c]; g = fig[c]; be = fibeta[c]; }
        else { int cc = c - DEEP_; x = ws[OFF_EMB + b * DEEP_ + cc]; g = eg[cc]; be = ebeta[cc]; }
        float sm = ws[OFF_ACC + c], sq = ws[OFF_ACC + 800 + c];
        float mean = sm * (1.f / BATCH);
        float var = sq * (1.f / BATCH) - mean * mean;
        float rstd = rsqrtf(var + EPS_);
        float v = fmaxf(g * (x - mean) * rstd + be, 0.f);
        part += v * fcw[c];
    }
    __shared__ float red[4];
#pragma unroll
    for (int off = 32; off > 0; off >>= 1) part += __shfl_down(part, off, 64);
    if ((tid & 63) == 0) red[tid >> 6] = part;
    __syncthreads();
    if (tid == 0) {
        float tot = red[0] + red[1] + red[2] + red[3] + fcb[0];
        out[b] = 1.f / (1.f + expf(-tot));
    }
}

extern "C" void kernel_launch(void* const* d_in, const int* in_sizes, int n_in,
                              void* d_out, int out_size, void* d_ws, size_t ws_size,
                              hipStream_t stream) {
    const int*   xi    = (const int*)d_in[0];
    const float* xv    = (const float*)d_in[1];
    const float* emb   = (const float*)d_in[2];
    const float* T3    = (const float*)d_in[3];
    const float* T2    = (const float*)d_in[4];
    const float* gc    = (const float*)d_in[5];
    const float* fi_w  = (const float*)d_in[6];
    const float* fig   = (const float*)d_in[8];
    const float* fibt  = (const float*)d_in[9];
    const float* emb_w = (const float*)d_in[10];
    const float* eg    = (const float*)d_in[12];
    const float* ebt   = (const float*)d_in[13];
    const float* fcw   = (const float*)d_in[14];
    const float* fcb   = (const float*)d_in[15];
    float* ws = (float*)d_ws;
    ushort* Abf = (ushort*)(ws + OFF_ABF);
    ushort* W2  = (ushort*)(ws + OFF_W2);
    ushort* WE  = (ushort*)(ws + OFF_WE);
    ushort* FMB = (ushort*)(ws + OFF_FMB);
    float* out = (float*)d_out;

    hipLaunchKernelGGL(kprep, dim3(1), dim3(256), 0, stream, T3, T2, ws);
    hipLaunchKernelGGL(kwr2, dim3(384), dim3(256), 0, stream, fi_w, W2);
    hipLaunchKernelGGL(kwe, dim3(KEP * 128 / 256), dim3(256), 0, stream, emb_w, WE);
    hipLaunchKernelGGL(kfeat, dim3(BATCH), dim3(256), 0, stream, xi, xv, emb, gc, ws, Abf, FMB);
    hipLaunchKernelGGL(kgemm3, dim3(800), dim3(512), 0, stream,
                       Abf, W2, ws + OFF_T, ws + OFF_TH, ws + OFF_ACC);
    hipLaunchKernelGGL(kegemm2, dim3(128), dim3(256), 0, stream,
                       FMB, WE, ws + OFF_EMB, ws + OFF_ACC);
    hipLaunchKernelGGL(kfinal, dim3(BATCH), dim3(256), 0, stream,
                       fig, fibt, eg, ebt, fcw, fcb, ws, out);
}

// Round 6
// 92.579 us; speedup vs baseline: 10.1389x; 1.4825x over previous
//
#include <hip/hip_runtime.h>
#include <hip/hip_bf16.h>

#define BATCH 4096
#define FIELDS_ 39
#define NUMF 13
#define CATF 26
#define DD 16
#define MM 16
#define VV 100000
#define DEEP_ 400
#define QQ 741
#define QPAD 768
#define KE 624      // FIELDS*D
#define KEP 640     // padded K for emb branch
#define NEP 512     // padded N for emb branch
#define N1 6400     // DEEP*M (n = kcol*16 + m)
#define NKTE 20     // KEP/32
#define NT_ 24      // QPAD/32
#define EPS_ 1e-5f

// workspace layout (float offsets)
#define OFF_ABF 0                            // ushort A[b][768] row-major
#define OFF_T   (BATCH*QPAD/2)               // f32 t[b][m]
#define OFF_W2  (OFF_T + BATCH*MM)           // ushort W2[n][768] row-major
#define OFF_WE  (OFF_W2 + N1*QPAD/2)         // ushort WE[n][640] row-major (n pad 512)
#define OFF_FMB (OFF_WE + NEP*KEP/2)         // ushort fm2[b][k] stride KEP
#define OFF_TH  (OFF_FMB + BATCH*KEP/2)      // f32 th_pre[b][400]
#define OFF_EMB (OFF_TH + BATCH*DEEP_)       // f32 emb_pre[b][400]
#define OFF_ACC (OFF_EMB + BATCH*DEEP_)      // [0:400] th sum, [400:800] emb sum, [800:1200] th sq, [1200:1600] emb sq
#define OFF_T2S (OFF_ACC + 1600)
#define OFF_T3D (OFF_T2S + 16)
#define OFF_QIJ (OFF_T3D + 256)              // int table q -> (i<<8|j)

typedef __attribute__((ext_vector_type(8))) short bf16x8;
typedef __attribute__((ext_vector_type(4))) float f32x4;

__device__ __forceinline__ ushort f2bf(float v) {
    union { float f; unsigned u; } x; x.f = v;
    unsigned r = x.u + 0x7fff + ((x.u >> 16) & 1);
    return (ushort)(r >> 16);
}
__device__ __forceinline__ unsigned pack2(float a, float b) {
    return (unsigned)f2bf(a) | ((unsigned)f2bf(b) << 16);
}
__device__ __forceinline__ void async16(void* lds, const void* g) {
    __builtin_amdgcn_global_load_lds(
        (const __attribute__((address_space(1))) unsigned int*)g,
        (__attribute__((address_space(3))) unsigned int*)lds,
        16, 0, 0);
}

// ---------------- prep: scalars + W2 transpose + WE transpose (one dispatch) ----
__global__ __launch_bounds__(256) void kprep_all(const float* __restrict__ T3,
                                                 const float* __restrict__ T2,
                                                 const float* __restrict__ fi_w,
                                                 const float* __restrict__ emb_w,
                                                 float* __restrict__ ws,
                                                 ushort* __restrict__ W2,
                                                 ushort* __restrict__ WE) {
    __shared__ float tile[32][401];
    int bid = blockIdx.x, tid = threadIdx.x;
    if (bid == 0) {
        if (tid < MM) {
            float s = 0.f;
            for (int j = 0; j < DD * DD; ++j) s += T2[tid * DD * DD + j];
            ws[OFF_T2S + tid] = s;
        }
        if (tid < DD * MM) {
            int d = tid >> 4, m = tid & 15;
            ws[OFF_T3D + tid] = T3[(d * MM + m) * DD + d];
        }
        for (int i = tid; i < 1600; i += 256) ws[OFF_ACC + i] = 0.f;
        int* qij = (int*)(ws + OFF_QIJ);
        for (int q = tid; q < QPAD; q += 256) {
            int v = 0;
            if (q < QQ) {
                int i = 0, qq = q, cnt = FIELDS_ - 1;
                while (qq >= cnt) { qq -= cnt; ++i; cnt = FIELDS_ - 1 - i; }
                v = (i << 8) | (i + 1 + qq);
            }
            qij[q] = v;
        }
    } else if (bid <= 384) {
        // fi_w -> W2[n][768]: block = (kt, m), LDS transpose
        int kt = (bid - 1) >> 4, m = (bid - 1) & 15;
        for (int i = tid; i < 32 * 100; i += 256) {
            int ql = i / 100, c4 = i - ql * 100;
            int q = kt * 32 + ql;
            float4 v = make_float4(0.f, 0.f, 0.f, 0.f);
            if (q < QQ) v = *(const float4*)&fi_w[(q * MM + m) * DEEP_ + c4 * 4];
            tile[ql][c4 * 4 + 0] = v.x; tile[ql][c4 * 4 + 1] = v.y;
            tile[ql][c4 * 4 + 2] = v.z; tile[ql][c4 * 4 + 3] = v.w;
        }
        __syncthreads();
        for (int i = tid; i < 400 * 4; i += 256) {
            int kcol = i >> 2, cq = i & 3;
            unsigned r[4];
#pragma unroll
            for (int j = 0; j < 4; ++j)
                r[j] = pack2(tile[cq * 8 + 2 * j][kcol], tile[cq * 8 + 2 * j + 1][kcol]);
            *(uint4*)&W2[(long)(kcol * 16 + m) * QPAD + kt * 32 + cq * 8] =
                make_uint4(r[0], r[1], r[2], r[3]);
        }
    } else {
        // emb_w -> WE[n][640]: block = kt (0..19), LDS transpose
        int kt = bid - 385;
        for (int i = tid; i < 32 * 100; i += 256) {
            int kl = i / 100, c4 = i - kl * 100;
            int k = kt * 32 + kl;
            float4 v = make_float4(0.f, 0.f, 0.f, 0.f);
            if (k < KE) v = *(const float4*)&emb_w[k * DEEP_ + c4 * 4];
            tile[kl][c4 * 4 + 0] = v.x; tile[kl][c4 * 4 + 1] = v.y;
            tile[kl][c4 * 4 + 2] = v.z; tile[kl][c4 * 4 + 3] = v.w;
        }
        __syncthreads();
        for (int i = tid; i < 512 * 4; i += 256) {
            int n = i >> 2, cq = i & 3;
            uint4 o = make_uint4(0, 0, 0, 0);
            if (n < DEEP_) {
                unsigned r[4];
#pragma unroll
                for (int j = 0; j < 4; ++j)
                    r[j] = pack2(tile[cq * 8 + 2 * j][n], tile[cq * 8 + 2 * j + 1][n]);
                o = make_uint4(r[0], r[1], r[2], r[3]);
            }
            *(uint4*)&WE[(long)n * KEP + kt * 32 + cq * 8] = o;
        }
    }
}

// ---------------- feature kernel (unchanged) ----------------------------------
__global__ __launch_bounds__(256) void kfeat(const int* __restrict__ xi,
                                             const float* __restrict__ xv,
                                             const float* __restrict__ emb,
                                             const float* __restrict__ gc,
                                             float* __restrict__ ws,
                                             ushort* __restrict__ Abf,
                                             ushort* __restrict__ FMB) {
    __shared__ float row[KE];
    __shared__ float hsh[DD];
    __shared__ float gash[MM];
    int b = blockIdx.x, tid = threadIdx.x;
    for (int e = tid; e < KE; e += 256) {
        int f = e >> 4, d = e & 15;
        float v;
        if (f < NUMF) {
            v = xv[b * NUMF + f] * emb[(long)f * VV * DD + d];
        } else {
            int c = f - NUMF;
            int idxv = xi[b * CATF + c];
            v = emb[((long)(NUMF + c) * VV + idxv) * DD + d];
        }
        row[e] = v;
    }
    __syncthreads();
    for (int e = tid; e < KEP; e += 256)
        FMB[(long)b * KEP + e] = (e < KE) ? f2bf(row[e]) : (ushort)0;
    if (tid < DD) {
        float s = 0.f, s2 = 0.f;
        for (int f = 0; f < FIELDS_; ++f) { float v = row[f * DD + tid]; s += v; s2 += v * v; }
        hsh[tid] = 0.5f * (s * s - s2);
    }
    __syncthreads();
    if (tid < MM) {
        float g = 0.f;
        for (int d = 0; d < DD; ++d) g += hsh[d] * ws[OFF_T3D + d * MM + tid];
        gash[tid] = g;
    }
    __syncthreads();
    if (tid < MM) {
        float mx = -1e30f;
        for (int m = 0; m < MM; ++m) mx = fmaxf(mx, gash[m]);
        float se = 0.f;
        for (int m = 0; m < MM; ++m) se += expf(gash[m] - mx);
        ws[OFF_T + b * MM + tid] = expf(gash[tid] - mx) / se * ws[OFF_T2S + tid];
    }
    const int* qij = (const int*)(ws + OFF_QIJ);
    for (int q = tid; q < QPAD; q += 256) {
        float av = 0.f;
        if (q < QQ) {
            int ij = qij[q];
            int i = ij >> 8, j = ij & 255;
            float dot = 0.f;
#pragma unroll
            for (int d = 0; d < DD; ++d) dot += row[i * DD + d] * row[j * DD + d];
            av = dot * gc[q];
        }
        Abf[(long)b * QPAD + q] = f2bf(av);
    }
}

// ---------------- unified GEMM dispatch ---------------------------------------
// 2-slot double-buffered pipeline, 1 barrier/K-step, prefetch before MFMA.
// Blocks 0..799: main GEMM (swapped operands, T-contraction epilogue).
// Blocks 800..863: emb GEMM (natural operands, coalesced store + stats).
__device__ __forceinline__ void pipeline(const ushort* As, const ushort* Bs0,
                                         const ushort* Bs1, ushort* lds0, ushort* lds1,
                                         int tid, int nt, int f1b, int f2b, int sw,
                                         f32x4 (*acc)[4]) {
#define STAGEP(L, T) { \
    async16((L) + tid * 8, As + (T) * 32); \
    async16((L) + 4096 + tid * 8, Bs0 + (T) * 32); \
    async16((L) + 8192 + tid * 8, Bs1 + (T) * 32); }
    STAGEP(lds0, 0);
    asm volatile("s_waitcnt vmcnt(0)" ::: "memory");
    __builtin_amdgcn_s_barrier();
    for (int t = 0; t < nt; ++t) {
        __builtin_amdgcn_sched_barrier(0);
        ushort* cur = (t & 1) ? lds1 : lds0;
        ushort* nxt = (t & 1) ? lds0 : lds1;
        bf16x8 f1[4], f2[4];
#pragma unroll
        for (int r = 0; r < 4; ++r) f1[r] = *(const bf16x8*)&cur[f1b + r * 512 + sw];
#pragma unroll
        for (int c = 0; c < 4; ++c) f2[c] = *(const bf16x8*)&cur[f2b + c * 512 + sw];
        if (t + 1 < nt) STAGEP(nxt, t + 1);
        __builtin_amdgcn_s_setprio(1);
#pragma unroll
        for (int r = 0; r < 4; ++r)
#pragma unroll
            for (int c = 0; c < 4; ++c)
                acc[r][c] = __builtin_amdgcn_mfma_f32_16x16x32_bf16(f1[r], f2[c], acc[r][c], 0, 0, 0);
        __builtin_amdgcn_s_setprio(0);
        if (t + 1 < nt) { asm volatile("s_waitcnt vmcnt(0)" ::: "memory"); }
        __builtin_amdgcn_s_barrier();
    }
#undef STAGEP
}

__global__ __launch_bounds__(512, 4) void kgemms(const ushort* __restrict__ Abf,
                                                 const ushort* __restrict__ W2,
                                                 const ushort* __restrict__ FMB,
                                                 const ushort* __restrict__ WE,
                                                 const float* __restrict__ Tmat,
                                                 float* __restrict__ TH,
                                                 float* __restrict__ EMB,
                                                 float* __restrict__ ACC) {
    __shared__ ushort lds0[12288];   // slot: A[128][32] | B[256][32]
    __shared__ ushort lds1[12288];
    __shared__ float red[512];
    int tid = threadIdx.x;
    int lane = tid & 63, wid = tid >> 6;
    int wb = wid >> 2, wn = wid & 3;
    int kq = lane >> 4, lr = lane & 15;
    int arow = tid >> 2, ac = tid & 3;
    int csw = (ac ^ ((arow >> 1) & 3)) * 8;   // inverse-swizzled global source
    int sw = (kq ^ ((lr >> 1) & 3)) * 8;      // swizzled LDS fragment read
    red[tid < 512 ? tid : 0] = 0.f;
    f32x4 acc[4][4] = {};
    int wg = blockIdx.x;

    if (wg < 800) {
        int s = (wg & 7) * 100 + (wg >> 3);    // XCD swizzle, 800 % 8 == 0
        int n0 = (s >> 5) * 256, b0 = (s & 31) * 128;
        const ushort* As  = Abf + (long)(b0 + arow) * QPAD + csw;
        const ushort* Bs0 = W2 + (long)(n0 + arow) * QPAD + csw;
        const ushort* Bs1 = W2 + (long)(n0 + 128 + arow) * QPAD + csw;
        pipeline(As, Bs0, Bs1, lds0, lds1, tid, NT_,
                 4096 + (wn * 64 + lr) * 32, (wb * 64 + lr) * 32, sw, acc);
        // epilogue: acc[r][cg][j] = C'[n = n0+wn*64+r*16+kq*4+j][b = b0+wb*64+cg*16+lr]
        float ls[4] = {0.f, 0.f, 0.f, 0.f}, ls2[4] = {0.f, 0.f, 0.f, 0.f};
#pragma unroll
        for (int cg = 0; cg < 4; ++cg) {
            int bloc = wb * 64 + cg * 16 + lr;
            float4 t4 = *(const float4*)&Tmat[(b0 + bloc) * 16 + kq * 4];
#pragma unroll
            for (int r = 0; r < 4; ++r) {
                float v = acc[r][cg][0] * t4.x + acc[r][cg][1] * t4.y +
                          acc[r][cg][2] * t4.z + acc[r][cg][3] * t4.w;
                v += __shfl_xor(v, 16);
                v += __shfl_xor(v, 32);
                ls[r] += v; ls2[r] += v * v;
                if (lane < 16)
                    TH[(b0 + bloc) * DEEP_ + (n0 >> 4) + wn * 4 + r] = v;
            }
        }
#pragma unroll
        for (int r = 0; r < 4; ++r) {
            float a = ls[r], b2 = ls2[r];
            a += __shfl_xor(a, 8, 16); b2 += __shfl_xor(b2, 8, 16);
            a += __shfl_xor(a, 4, 16); b2 += __shfl_xor(b2, 4, 16);
            a += __shfl_xor(a, 2, 16); b2 += __shfl_xor(b2, 2, 16);
            a += __shfl_xor(a, 1, 16); b2 += __shfl_xor(b2, 1, 16);
            if (lane == 0) {
                atomicAdd(&red[wn * 4 + r], a);
                atomicAdd(&red[16 + wn * 4 + r], b2);
            }
        }
        __syncthreads();
        if (tid < 16) {
            atomicAdd(&ACC[(n0 >> 4) + tid], red[tid]);
            atomicAdd(&ACC[800 + (n0 >> 4) + tid], red[16 + tid]);
        }
    } else {
        int e = wg - 800;
        int se = (e & 7) * 8 + (e >> 3);       // 64 % 8 == 0
        int n0 = (se >> 5) * 256, b0 = (se & 31) * 128;
        const ushort* As  = FMB + (long)(b0 + arow) * KEP + csw;
        const ushort* Bs0 = WE + (long)(n0 + arow) * KEP + csw;
        const ushort* Bs1 = WE + (long)(n0 + 128 + arow) * KEP + csw;
        pipeline(As, Bs0, Bs1, lds0, lds1, tid, NKTE,
                 (wb * 64 + lr) * 32, 4096 + (wn * 64 + lr) * 32, sw, acc);
        // epilogue: acc[r][cg][j] = C[b = b0+wb*64+r*16+kq*4+j][n = n0+wn*64+cg*16+lr]
#pragma unroll
        for (int cg = 0; cg < 4; ++cg) {
            int ncl = wn * 64 + cg * 16 + lr;
            int nc = n0 + ncl;
            float ls = 0.f, ls2 = 0.f;
#pragma unroll
            for (int r = 0; r < 4; ++r) {
#pragma unroll
                for (int j = 0; j < 4; ++j) {
                    float v = acc[r][cg][j];
                    int brow = b0 + wb * 64 + r * 16 + kq * 4 + j;
                    if (nc < DEEP_) EMB[brow * DEEP_ + nc] = v;
                    ls += v; ls2 += v * v;
                }
            }
            ls += __shfl_xor(ls, 16);  ls += __shfl_xor(ls, 32);
            ls2 += __shfl_xor(ls2, 16); ls2 += __shfl_xor(ls2, 32);
            if (lane < 16 && nc < DEEP_) {
                atomicAdd(&red[ncl], ls);
                atomicAdd(&red[256 + ncl], ls2);
            }
        }
        __syncthreads();
        if (tid < 256) {
            int nc = n0 + tid;
            if (nc < DEEP_) {
                atomicAdd(&ACC[400 + nc], red[tid]);
                atomicAdd(&ACC[1200 + nc], red[256 + tid]);
            }
        }
    }
}

// ---------------- final BN + ReLU + FC + sigmoid -------------------------------
__global__ __launch_bounds__(256) void kfinal(const float* fig, const float* fibeta,
                                              const float* eg, const float* ebeta,
                                              const float* fcw, const float* fcb,
                                              const float* ws, float* out) {
    int b = blockIdx.x, tid = threadIdx.x;
    float part = 0.f;
    for (int c = tid; c < 800; c += 256) {
        float x, g, be;
        if (c < DEEP_) { x = ws[OFF_TH + b * DEEP_ + c]; g = fig[c]; be = fibeta[c]; }
        else { int cc = c - DEEP_; x = ws[OFF_EMB + b * DEEP_ + cc]; g = eg[cc]; be = ebeta[cc]; }
        float sm = ws[OFF_ACC + c], sq = ws[OFF_ACC + 800 + c];
        float mean = sm * (1.f / BATCH);
        float var = sq * (1.f / BATCH) - mean * mean;
        float rstd = rsqrtf(var + EPS_);
        float v = fmaxf(g * (x - mean) * rstd + be, 0.f);
        part += v * fcw[c];
    }
    __shared__ float red[4];
#pragma unroll
    for (int off = 32; off > 0; off >>= 1) part += __shfl_down(part, off, 64);
    if ((tid & 63) == 0) red[tid >> 6] = part;
    __syncthreads();
    if (tid == 0) {
        float tot = red[0] + red[1] + red[2] + red[3] + fcb[0];
        out[b] = 1.f / (1.f + expf(-tot));
    }
}

extern "C" void kernel_launch(void* const* d_in, const int* in_sizes, int n_in,
                              void* d_out, int out_size, void* d_ws, size_t ws_size,
                              hipStream_t stream) {
    const int*   xi    = (const int*)d_in[0];
    const float* xv    = (const float*)d_in[1];
    const float* emb   = (const float*)d_in[2];
    const float* T3    = (const float*)d_in[3];
    const float* T2    = (const float*)d_in[4];
    const float* gc    = (const float*)d_in[5];
    const float* fi_w  = (const float*)d_in[6];
    const float* fig   = (const float*)d_in[8];
    const float* fibt  = (const float*)d_in[9];
    const float* emb_w = (const float*)d_in[10];
    const float* eg    = (const float*)d_in[12];
    const float* ebt   = (const float*)d_in[13];
    const float* fcw   = (const float*)d_in[14];
    const float* fcb   = (const float*)d_in[15];
    float* ws = (float*)d_ws;
    ushort* Abf = (ushort*)(ws + OFF_ABF);
    ushort* W2  = (ushort*)(ws + OFF_W2);
    ushort* WE  = (ushort*)(ws + OFF_WE);
    ushort* FMB = (ushort*)(ws + OFF_FMB);
    float* out = (float*)d_out;

    hipLaunchKernelGGL(kprep_all, dim3(405), dim3(256), 0, stream,
                       T3, T2, fi_w, emb_w, ws, W2, WE);
    hipLaunchKernelGGL(kfeat, dim3(BATCH), dim3(256), 0, stream, xi, xv, emb, gc, ws, Abf, FMB);
    hipLaunchKernelGGL(kgemms, dim3(864), dim3(512), 0, stream,
                       Abf, W2, FMB, WE, ws + OFF_T, ws + OFF_TH, ws + OFF_EMB, ws + OFF_ACC);
    hipLaunchKernelGGL(kfinal, dim3(BATCH), dim3(256), 0, stream,
                       fig, fibt, eg, ebt, fcw, fcb, ws, out);
}

// Round 8
// 91.494 us; speedup vs baseline: 10.2591x; 1.0119x over previous
//
#include <hip/hip_runtime.h>
#include <hip/hip_bf16.h>

#define BATCH 4096
#define FIELDS_ 39
#define NUMF 13
#define CATF 26
#define DD 16
#define MM 16
#define VV 100000
#define DEEP_ 400
#define QQ 741
#define QPAD 768
#define KE 624      // FIELDS*D
#define KEP 640     // padded K for emb branch
#define NEP 512     // padded N for emb branch
#define N1 6400     // DEEP*M (n = kcol*16 + m)
#define NKTE 20     // KEP/32
#define NT_ 24      // QPAD/32
#define EPS_ 1e-5f

// workspace layout (float offsets)
#define OFF_ABF 0                            // ushort A[b][768] row-major
#define OFF_T   (BATCH*QPAD/2)               // f32 t[b][m]
#define OFF_W2  (OFF_T + BATCH*MM)           // ushort W2[n][768] row-major
#define OFF_WE  (OFF_W2 + N1*QPAD/2)         // ushort WE[n][640] row-major (n pad 512)
#define OFF_FMB (OFF_WE + NEP*KEP/2)         // ushort fm2[b][k] stride KEP
#define OFF_TH  (OFF_FMB + BATCH*KEP/2)      // f32 th_pre[b][400]
#define OFF_EMB (OFF_TH + BATCH*DEEP_)       // f32 emb_pre[b][400]
#define OFF_ACC (OFF_EMB + BATCH*DEEP_)      // [0:800] sums, [800:1600] sumsq
#define OFF_T2S (OFF_ACC + 1600)
#define OFF_T3D (OFF_T2S + 16)

typedef __attribute__((ext_vector_type(8))) short bf16x8;
typedef __attribute__((ext_vector_type(4))) float f32x4;

__device__ __forceinline__ ushort f2bf(float v) {
    union { float f; unsigned u; } x; x.f = v;
    unsigned r = x.u + 0x7fff + ((x.u >> 16) & 1);
    return (ushort)(r >> 16);
}
__device__ __forceinline__ unsigned pack2(float a, float b) {
    return (unsigned)f2bf(a) | ((unsigned)f2bf(b) << 16);
}
__device__ __forceinline__ void async16(void* lds, const void* g) {
    __builtin_amdgcn_global_load_lds(
        (const __attribute__((address_space(1))) unsigned int*)g,
        (__attribute__((address_space(3))) unsigned int*)lds,
        16, 0, 0);
}

// ---------------- 1-block scalar prep -----------------------------------------
__global__ __launch_bounds__(256) void kprep0(const float* __restrict__ T3,
                                              const float* __restrict__ T2,
                                              float* __restrict__ ws) {
    int tid = threadIdx.x;
    if (tid < MM) {
        float s = 0.f;
        for (int j = 0; j < DD * DD; ++j) s += T2[tid * DD * DD + j];
        ws[OFF_T2S + tid] = s;
    }
    if (tid < DD * MM) {
        int d = tid >> 4, m = tid & 15;
        ws[OFF_T3D + tid] = T3[(d * MM + m) * DD + d];
    }
    for (int i = tid; i < 1600; i += 256) ws[OFF_ACC + i] = 0.f;
}

// ---------------- merged: feat (0..4095) | W2 transpose | WE transpose ---------
__global__ __launch_bounds__(256) void kbig(const int* __restrict__ xi,
                                            const float* __restrict__ xv,
                                            const float* __restrict__ emb,
                                            const float* __restrict__ gc,
                                            const float* __restrict__ fi_w,
                                            const float* __restrict__ emb_w,
                                            float* __restrict__ ws,
                                            ushort* __restrict__ Abf,
                                            ushort* __restrict__ FMB,
                                            ushort* __restrict__ W2,
                                            ushort* __restrict__ WE) {
    __shared__ float smem[4200];
    int bid = blockIdx.x, tid = threadIdx.x;

    if (bid < BATCH) {
        // ---- feature block ----
        float* row = smem;             // 624
        float* hsh = smem + 624;       // 16
        float* gash = smem + 640;      // 16
        ushort* stA = (ushort*)(smem + 656);   // 768 ushorts
        ushort* stF = stA + QPAD;              // 640 ushorts
        int b = bid;
        for (int e = tid; e < KE; e += 256) {
            int f = e >> 4, d = e & 15;
            float v;
            if (f < NUMF) {
                v = xv[b * NUMF + f] * emb[(long)f * VV * DD + d];
            } else {
                int c = f - NUMF;
                int idxv = xi[b * CATF + c];
                v = emb[((long)(NUMF + c) * VV + idxv) * DD + d];
            }
            row[e] = v;
        }
        __syncthreads();
        for (int e = tid; e < KEP; e += 256)
            stF[e] = (e < KE) ? f2bf(row[e]) : (ushort)0;
        if (tid < DD) {
            float s = 0.f, s2 = 0.f;
            for (int f = 0; f < FIELDS_; ++f) { float v = row[f * DD + tid]; s += v; s2 += v * v; }
            hsh[tid] = 0.5f * (s * s - s2);
        }
        __syncthreads();
        if (tid < MM) {
            float g = 0.f;
            for (int d = 0; d < DD; ++d) g += hsh[d] * ws[OFF_T3D + d * MM + tid];
            gash[tid] = g;
        }
        __syncthreads();
        if (tid < MM) {
            float mx = -1e30f;
            for (int m = 0; m < MM; ++m) mx = fmaxf(mx, gash[m]);
            float se = 0.f;
            for (int m = 0; m < MM; ++m) se += expf(gash[m] - mx);
            ws[OFF_T + b * MM + tid] = expf(gash[tid] - mx) / se * ws[OFF_T2S + tid];
        }
        for (int q = tid; q < QPAD; q += 256) {
            float av = 0.f;
            if (q < QQ) {
                int i = 0, qq = q, cnt = FIELDS_ - 1;
                while (qq >= cnt) { qq -= cnt; ++i; cnt = FIELDS_ - 1 - i; }
                int j = i + 1 + qq;
                float dot = 0.f;
#pragma unroll
                for (int d = 0; d < DD; ++d) dot += row[i * DD + d] * row[j * DD + d];
                av = dot * gc[q];
            }
            stA[q] = f2bf(av);
        }
        __syncthreads();
        if (tid < 96)
            *(uint4*)&Abf[(long)b * QPAD + tid * 8] = *(uint4*)&stA[tid * 8];
        else if (tid < 176)
            *(uint4*)&FMB[(long)b * KEP + (tid - 96) * 8] = *(uint4*)&stF[(tid - 96) * 8];
    } else if (bid < BATCH + 1536) {
        // ---- W2 transpose: fi_w -> W2[n][768]; block = (kt, m, chunk) ----
        int bt = bid - BATCH;
        int kt = bt >> 6, m = (bt >> 2) & 15, ch = bt & 3;
        float* tile = smem;   // [32][101]
        for (int i = tid; i < 32 * 25; i += 256) {
            int ql = i / 25, c4 = i - ql * 25;
            int q = kt * 32 + ql;
            float4 v = make_float4(0.f, 0.f, 0.f, 0.f);
            if (q < QQ) v = *(const float4*)&fi_w[(q * MM + m) * DEEP_ + ch * 100 + c4 * 4];
            tile[ql * 101 + c4 * 4 + 0] = v.x; tile[ql * 101 + c4 * 4 + 1] = v.y;
            tile[ql * 101 + c4 * 4 + 2] = v.z; tile[ql * 101 + c4 * 4 + 3] = v.w;
        }
        __syncthreads();
        for (int i = tid; i < 100 * 4; i += 256) {
            int lc = i >> 2, cq = i & 3;
            int kcol = ch * 100 + lc;
            unsigned r[4];
#pragma unroll
            for (int j = 0; j < 4; ++j)
                r[j] = pack2(tile[(cq * 8 + 2 * j) * 101 + lc], tile[(cq * 8 + 2 * j + 1) * 101 + lc]);
            *(uint4*)&W2[(long)(kcol * 16 + m) * QPAD + kt * 32 + cq * 8] =
                make_uint4(r[0], r[1], r[2], r[3]);
        }
    } else {
        // ---- WE transpose: emb_w -> WE[n][640]; block = (kt, chunk) ----
        int bt = bid - BATCH - 1536;
        int kt = bt >> 2, ch = bt & 3;
        float* tile = smem;   // [32][129]
        for (int i = tid; i < 32 * 32; i += 256) {
            int kl = i >> 5, c4 = i & 31;
            int k = kt * 32 + kl;
            int n = ch * 128 + c4 * 4;
            float4 v = make_float4(0.f, 0.f, 0.f, 0.f);
            if (k < KE && n < DEEP_) v = *(const float4*)&emb_w[k * DEEP_ + n];
            tile[kl * 129 + c4 * 4 + 0] = v.x; tile[kl * 129 + c4 * 4 + 1] = v.y;
            tile[kl * 129 + c4 * 4 + 2] = v.z; tile[kl * 129 + c4 * 4 + 3] = v.w;
        }
        __syncthreads();
        for (int i = tid; i < 128 * 4; i += 256) {
            int nl = i >> 2, cq = i & 3;
            int n = ch * 128 + nl;
            uint4 o = make_uint4(0, 0, 0, 0);
            if (n < DEEP_) {
                unsigned r[4];
#pragma unroll
                for (int j = 0; j < 4; ++j)
                    r[j] = pack2(tile[(cq * 8 + 2 * j) * 129 + nl], tile[(cq * 8 + 2 * j + 1) * 129 + nl]);
                o = make_uint4(r[0], r[1], r[2], r[3]);
            }
            if (n < NEP)
                *(uint4*)&WE[(long)n * KEP + kt * 32 + cq * 8] = o;
        }
    }
}

// ---------------- unified GEMM dispatch ---------------------------------------
// 3-slot counted-vmcnt pipeline. In-flight accounting (3 loads per STAGE):
//   prologue: stage(0),stage(1) -> 6 in flight; vmcnt(3) drains slot 0 only.
//   iter t:   stage(t+2) mid-iter -> 6 in flight at wait point;
//             vmcnt(3) drains slot t+1, keeps slot t+2's 3 loads across the barrier.
//   tail:     vmcnt(0) before the last iteration.
__device__ __forceinline__ void pipeline3(const ushort* As, const ushort* Bs0,
                                          const ushort* Bs1, ushort* lds,
                                          int tid, int nt, int f1b, int f2b, int sw,
                                          f32x4 (*acc)[4]) {
#define STAGEP(SL, T) { \
    ushort* L_ = lds + (SL) * 12288; \
    async16(L_ + tid * 8, As + (T) * 32); \
    async16(L_ + 4096 + tid * 8, Bs0 + (T) * 32); \
    async16(L_ + 8192 + tid * 8, Bs1 + (T) * 32); }
    STAGEP(0, 0); STAGEP(1, 1);
    asm volatile("s_waitcnt vmcnt(3)" ::: "memory");
    __builtin_amdgcn_s_barrier();
    int sl = 0;
    for (int t = 0; t < nt; ++t) {
        __builtin_amdgcn_sched_barrier(0);
        const ushort* cur = lds + sl * 12288;
        bf16x8 f1[4], f2[4];
#pragma unroll
        for (int r = 0; r < 4; ++r) f1[r] = *(const bf16x8*)&cur[f1b + r * 512 + sw];
#pragma unroll
        for (int c = 0; c < 4; ++c) f2[c] = *(const bf16x8*)&cur[f2b + c * 512 + sw];
        int sl2 = sl + 2; if (sl2 >= 3) sl2 -= 3;
        if (t + 2 < nt) STAGEP(sl2, t + 2);
        __builtin_amdgcn_s_setprio(1);
#pragma unroll
        for (int r = 0; r < 4; ++r)
#pragma unroll
            for (int c = 0; c < 4; ++c)
                acc[r][c] = __builtin_amdgcn_mfma_f32_16x16x32_bf16(f1[r], f2[c], acc[r][c], 0, 0, 0);
        __builtin_amdgcn_s_setprio(0);
        if (t + 1 < nt) {
            if (t + 2 < nt) { asm volatile("s_waitcnt vmcnt(3)" ::: "memory"); }
            else            { asm volatile("s_waitcnt vmcnt(0)" ::: "memory"); }
            __builtin_amdgcn_s_barrier();
        }
        sl = sl + 1; if (sl >= 3) sl -= 3;
    }
#undef STAGEP
}

__global__ __launch_bounds__(512, 4) void kgemms(const ushort* __restrict__ Abf,
                                                 const ushort* __restrict__ W2,
                                                 const ushort* __restrict__ FMB,
                                                 const ushort* __restrict__ WE,
                                                 const float* __restrict__ Tmat,
                                                 float* __restrict__ TH,
                                                 float* __restrict__ EMB,
                                                 float* __restrict__ ACC) {
    __shared__ ushort ldsbuf[3 * 12288];   // slot: A[128][32] | B[256][32]
    __shared__ float red[512];
    int tid = threadIdx.x;
    int lane = tid & 63, wid = tid >> 6;
    int wb = wid >> 2, wn = wid & 3;
    int kq = lane >> 4, lr = lane & 15;
    int arow = tid >> 2, ac = tid & 3;
    int csw = (ac ^ ((arow >> 1) & 3)) * 8;   // inverse-swizzled global source
    int sw = (kq ^ ((lr >> 1) & 3)) * 8;      // swizzled LDS fragment read
    red[tid] = 0.f;
    f32x4 acc[4][4] = {};
    int wg = blockIdx.x;

    if (wg < 800) {
        int s = (wg & 7) * 100 + (wg >> 3);    // XCD swizzle (800 % 8 == 0)
        int n0 = (s >> 5) * 256, b0 = (s & 31) * 128;
        const ushort* As  = Abf + (long)(b0 + arow) * QPAD + csw;
        const ushort* Bs0 = W2 + (long)(n0 + arow) * QPAD + csw;
        const ushort* Bs1 = W2 + (long)(n0 + 128 + arow) * QPAD + csw;
        pipeline3(As, Bs0, Bs1, ldsbuf, tid, NT_,
                  4096 + (wn * 64 + lr) * 32, (wb * 64 + lr) * 32, sw, acc);
        // acc[r][cg][j] = C'[n = n0+wn*64+r*16+kq*4+j][b = b0+wb*64+cg*16+lr]
        float* tbuf = (float*)ldsbuf;          // [128][17] floats, inside slot 0
        float ls[4] = {0.f, 0.f, 0.f, 0.f}, ls2[4] = {0.f, 0.f, 0.f, 0.f};
#pragma unroll
        for (int cg = 0; cg < 4; ++cg) {
            int bloc = wb * 64 + cg * 16 + lr;
            float4 t4 = *(const float4*)&Tmat[(b0 + bloc) * 16 + kq * 4];
#pragma unroll
            for (int r = 0; r < 4; ++r) {
                float v = acc[r][cg][0] * t4.x + acc[r][cg][1] * t4.y +
                          acc[r][cg][2] * t4.z + acc[r][cg][3] * t4.w;
                v += __shfl_xor(v, 16);
                v += __shfl_xor(v, 32);
                ls[r] += v; ls2[r] += v * v;
                if (kq == r) tbuf[bloc * 17 + wn * 4 + r] = v;
            }
        }
#pragma unroll
        for (int r = 0; r < 4; ++r) {
            float a = ls[r], b2 = ls2[r];
            a += __shfl_xor(a, 8, 16); b2 += __shfl_xor(b2, 8, 16);
            a += __shfl_xor(a, 4, 16); b2 += __shfl_xor(b2, 4, 16);
            a += __shfl_xor(a, 2, 16); b2 += __shfl_xor(b2, 2, 16);
            a += __shfl_xor(a, 1, 16); b2 += __shfl_xor(b2, 1, 16);
            if (lane == 0) {
                atomicAdd(&red[wn * 4 + r], a);
                atomicAdd(&red[16 + wn * 4 + r], b2);
            }
        }
        __syncthreads();
        if (tid < 16) {
            atomicAdd(&ACC[(n0 >> 4) + tid], red[tid]);
            atomicAdd(&ACC[800 + (n0 >> 4) + tid], red[16 + tid]);
        }
        {
            int rowl = tid >> 2, qf = tid & 3;
            float o0 = tbuf[rowl * 17 + qf * 4 + 0];
            float o1 = tbuf[rowl * 17 + qf * 4 + 1];
            float o2 = tbuf[rowl * 17 + qf * 4 + 2];
            float o3 = tbuf[rowl * 17 + qf * 4 + 3];
            *(float4*)&TH[(b0 + rowl) * DEEP_ + (n0 >> 4) + qf * 4] =
                make_float4(o0, o1, o2, o3);
        }
    } else {
        int e = wg - 800;
        int se = (e & 7) * 8 + (e >> 3);       // 64 % 8 == 0
        int n0 = (se >> 5) * 256, b0 = (se & 31) * 128;
        const ushort* As  = FMB + (long)(b0 + arow) * KEP + csw;
        const ushort* Bs0 = WE + (long)(n0 + arow) * KEP + csw;
        const ushort* Bs1 = WE + (long)(n0 + 128 + arow) * KEP + csw;
        pipeline3(As, Bs0, Bs1, ldsbuf, tid, NKTE,
                  (wb * 64 + lr) * 32, 4096 + (wn * 64 + lr) * 32, sw, acc);
        // acc[r][cg][j] = C[b = b0+wb*64+r*16+kq*4+j][n = n0+wn*64+cg*16+lr]
#pragma unroll
        for (int cg = 0; cg < 4; ++cg) {
            int ncl = wn * 64 + cg * 16 + lr;
            int nc = n0 + ncl;
            float ls = 0.f, ls2 = 0.f;
#pragma unroll
            for (int r = 0; r < 4; ++r) {
#pragma unroll
                for (int j = 0; j < 4; ++j) {
                    float v = acc[r][cg][j];
                    int brow = b0 + wb * 64 + r * 16 + kq * 4 + j;
                    if (nc < DEEP_) EMB[brow * DEEP_ + nc] = v;
                    ls += v; ls2 += v * v;
                }
            }
            ls += __shfl_xor(ls, 16);  ls += __shfl_xor(ls, 32);
            ls2 += __shfl_xor(ls2, 16); ls2 += __shfl_xor(ls2, 32);
            if (lane < 16 && nc < DEEP_) {
                atomicAdd(&red[ncl], ls);
                atomicAdd(&red[256 + ncl], ls2);
            }
        }
        __syncthreads();
        if (tid < 256) {
            int nc = n0 + tid;
            if (nc < DEEP_) {
                atomicAdd(&ACC[400 + nc], red[tid]);
                atomicAdd(&ACC[1200 + nc], red[256 + tid]);
            }
        }
    }
}

// ---------------- final BN + ReLU + FC + sigmoid -------------------------------
__global__ __launch_bounds__(256) void kfinal(const float* __restrict__ fig,
                                              const float* __restrict__ fibeta,
                                              const float* __restrict__ eg,
                                              const float* __restrict__ ebeta,
                                              const float* __restrict__ fcw,
                                              const float* __restrict__ fcb,
                                              const float* __restrict__ ws,
                                              float* __restrict__ out) {
    int b = blockIdx.x, tid = threadIdx.x;
    float part = 0.f;
    if (tid < 200) {
        int c = tid * 4;
        int loc = (c < DEEP_) ? c : c - DEEP_;
        const float* xp = (c < DEEP_) ? &ws[OFF_TH + b * DEEP_ + loc]
                                      : &ws[OFF_EMB + b * DEEP_ + loc];
        float4 x = *(const float4*)xp;
        float4 g = *(const float4*)((c < DEEP_) ? &fig[loc] : &eg[loc]);
        float4 be = *(const float4*)((c < DEEP_) ? &fibeta[loc] : &ebeta[loc]);
        float4 sm = *(const float4*)&ws[OFF_ACC + c];
        float4 sq = *(const float4*)&ws[OFF_ACC + 800 + c];
        float4 w = *(const float4*)&fcw[c];
        const float* xv_ = (const float*)&x; const float* gv = (const float*)&g;
        const float* bev = (const float*)&be; const float* smv = (const float*)&sm;
        const float* sqv = (const float*)&sq; const float* wv = (const float*)&w;
#pragma unroll
        for (int j = 0; j < 4; ++j) {
            float mean = smv[j] * (1.f / BATCH);
            float var = sqv[j] * (1.f / BATCH) - mean * mean;
            float rstd = rsqrtf(var + EPS_);
            float v = fmaxf(gv[j] * (xv_[j] - mean) * rstd + bev[j], 0.f);
            part += v * wv[j];
        }
    }
    __shared__ float red[4];
#pragma unroll
    for (int off = 32; off > 0; off >>= 1) part += __shfl_down(part, off, 64);
    if ((tid & 63) == 0) red[tid >> 6] = part;
    __syncthreads();
    if (tid == 0) {
        float tot = red[0] + red[1] + red[2] + red[3] + fcb[0];
        out[b] = 1.f / (1.f + expf(-tot));
    }
}

extern "C" void kernel_launch(void* const* d_in, const int* in_sizes, int n_in,
                              void* d_out, int out_size, void* d_ws, size_t ws_size,
                              hipStream_t stream) {
    const int*   xi    = (const int*)d_in[0];
    const float* xv    = (const float*)d_in[1];
    const float* emb   = (const float*)d_in[2];
    const float* T3    = (const float*)d_in[3];
    const float* T2    = (const float*)d_in[4];
    const float* gc    = (const float*)d_in[5];
    const float* fi_w  = (const float*)d_in[6];
    const float* fig   = (const float*)d_in[8];
    const float* fibt  = (const float*)d_in[9];
    const float* emb_w = (const float*)d_in[10];
    const float* eg    = (const float*)d_in[12];
    const float* ebt   = (const float*)d_in[13];
    const float* fcw   = (const float*)d_in[14];
    const float* fcb   = (const float*)d_in[15];
    float* ws = (float*)d_ws;
    ushort* Abf = (ushort*)(ws + OFF_ABF);
    ushort* W2  = (ushort*)(ws + OFF_W2);
    ushort* WE  = (ushort*)(ws + OFF_WE);
    ushort* FMB = (ushort*)(ws + OFF_FMB);
    float* out = (float*)d_out;

    hipLaunchKernelGGL(kprep0, dim3(1), dim3(256), 0, stream, T3, T2, ws);
    hipLaunchKernelGGL(kbig, dim3(BATCH + 1536 + 80), dim3(256), 0, stream,
                       xi, xv, emb, gc, fi_w, emb_w, ws, Abf, FMB, W2, WE);
    hipLaunchKernelGGL(kgemms, dim3(864), dim3(512), 0, stream,
                       Abf, W2, FMB, WE, ws + OFF_T, ws + OFF_TH, ws + OFF_EMB, ws + OFF_ACC);
    hipLaunchKernelGGL(kfinal, dim3(BATCH), dim3(256), 0, stream,
                       fig, fibt, eg, ebt, fcw, fcb, ws, out);
}

// Round 9
// 89.470 us; speedup vs baseline: 10.4912x; 1.0226x over previous
//
#include <hip/hip_runtime.h>
#include <hip/hip_bf16.h>

#define BATCH 4096
#define FIELDS_ 39
#define NUMF 13
#define CATF 26
#define DD 16
#define MM 16
#define VV 100000
#define DEEP_ 400
#define QQ 741
#define QPAD 768
#define KE 624      // FIELDS*D
#define KEP 640     // padded K for emb branch
#define NEP 512     // padded N for emb branch
#define N1 6400     // DEEP*M (n = kcol*16 + m)
#define NKTE 20     // KEP/32
#define NT_ 24      // QPAD/32
#define EPS_ 1e-5f

// workspace layout (float offsets)
#define OFF_ABF 0                            // ushort A[b][768] row-major
#define OFF_T   (BATCH*QPAD/2)               // f32 t[b][m]
#define OFF_W2  (OFF_T + BATCH*MM)           // ushort W2[n][768] row-major
#define OFF_WE  (OFF_W2 + N1*QPAD/2)         // ushort WE[n][640] row-major (n pad 512)
#define OFF_FMB (OFF_WE + NEP*KEP/2)         // ushort fm2[b][k] stride KEP
#define OFF_TH  (OFF_FMB + BATCH*KEP/2)      // f32 th_pre[b][400]
#define OFF_EMB (OFF_TH + BATCH*DEEP_)       // f32 emb_pre[b][400]
#define OFF_ACC (OFF_EMB + BATCH*DEEP_)      // [0:800] sums, [800:1600] sumsq
#define OFF_T2S (OFF_ACC + 1600)
#define OFF_T3D (OFF_T2S + 16)

typedef __attribute__((ext_vector_type(8))) short bf16x8;
typedef __attribute__((ext_vector_type(4))) float f32x4;

__device__ __forceinline__ ushort f2bf(float v) {
    union { float f; unsigned u; } x; x.f = v;
    unsigned r = x.u + 0x7fff + ((x.u >> 16) & 1);
    return (ushort)(r >> 16);
}
__device__ __forceinline__ unsigned pack2(float a, float b) {
    return (unsigned)f2bf(a) | ((unsigned)f2bf(b) << 16);
}
__device__ __forceinline__ void async16(void* lds, const void* g) {
    __builtin_amdgcn_global_load_lds(
        (const __attribute__((address_space(1))) unsigned int*)g,
        (__attribute__((address_space(3))) unsigned int*)lds,
        16, 0, 0);
}

// ---------------- 1-block scalar prep -----------------------------------------
__global__ __launch_bounds__(256) void kprep0(const float* __restrict__ T3,
                                              const float* __restrict__ T2,
                                              float* __restrict__ ws) {
    int tid = threadIdx.x;
    if (tid < MM) {
        float s = 0.f;
        for (int j = 0; j < DD * DD; ++j) s += T2[tid * DD * DD + j];
        ws[OFF_T2S + tid] = s;
    }
    if (tid < DD * MM) {
        int d = tid >> 4, m = tid & 15;
        ws[OFF_T3D + tid] = T3[(d * MM + m) * DD + d];
    }
    for (int i = tid; i < 1600; i += 256) ws[OFF_ACC + i] = 0.f;
}

// ---------------- merged: feat (0..4095) | W2 transpose | WE transpose ---------
__global__ __launch_bounds__(256) void kbig(const int* __restrict__ xi,
                                            const float* __restrict__ xv,
                                            const float* __restrict__ emb,
                                            const float* __restrict__ gc,
                                            const float* __restrict__ fi_w,
                                            const float* __restrict__ emb_w,
                                            float* __restrict__ ws,
                                            ushort* __restrict__ Abf,
                                            ushort* __restrict__ FMB,
                                            ushort* __restrict__ W2,
                                            ushort* __restrict__ WE) {
    __shared__ float smem[4200];
    int bid = blockIdx.x, tid = threadIdx.x;

    if (bid < BATCH) {
        // ---- feature block ----
        float* row = smem;             // 624
        float* hsh = smem + 624;       // 16
        float* gash = smem + 640;      // 16
        ushort* stA = (ushort*)(smem + 656);   // 768 ushorts
        ushort* stF = stA + QPAD;              // 640 ushorts
        int b = bid;
        for (int e = tid; e < KE; e += 256) {
            int f = e >> 4, d = e & 15;
            float v;
            if (f < NUMF) {
                v = xv[b * NUMF + f] * emb[(long)f * VV * DD + d];
            } else {
                int c = f - NUMF;
                int idxv = xi[b * CATF + c];
                v = emb[((long)(NUMF + c) * VV + idxv) * DD + d];
            }
            row[e] = v;
        }
        __syncthreads();
        for (int e = tid; e < KEP; e += 256)
            stF[e] = (e < KE) ? f2bf(row[e]) : (ushort)0;
        if (tid < DD) {
            float s = 0.f, s2 = 0.f;
            for (int f = 0; f < FIELDS_; ++f) { float v = row[f * DD + tid]; s += v; s2 += v * v; }
            hsh[tid] = 0.5f * (s * s - s2);
        }
        __syncthreads();
        if (tid < MM) {
            float g = 0.f;
            for (int d = 0; d < DD; ++d) g += hsh[d] * ws[OFF_T3D + d * MM + tid];
            gash[tid] = g;
        }
        __syncthreads();
        if (tid < MM) {
            float mx = -1e30f;
            for (int m = 0; m < MM; ++m) mx = fmaxf(mx, gash[m]);
            float se = 0.f;
            for (int m = 0; m < MM; ++m) se += expf(gash[m] - mx);
            ws[OFF_T + b * MM + tid] = expf(gash[tid] - mx) / se * ws[OFF_T2S + tid];
        }
        for (int q = tid; q < QPAD; q += 256) {
            float av = 0.f;
            if (q < QQ) {
                int i = 0, qq = q, cnt = FIELDS_ - 1;
                while (qq >= cnt) { qq -= cnt; ++i; cnt = FIELDS_ - 1 - i; }
                int j = i + 1 + qq;
                float dot = 0.f;
#pragma unroll
                for (int d = 0; d < DD; ++d) dot += row[i * DD + d] * row[j * DD + d];
                av = dot * gc[q];
            }
            stA[q] = f2bf(av);
        }
        __syncthreads();
        if (tid < 96)
            *(uint4*)&Abf[(long)b * QPAD + tid * 8] = *(uint4*)&stA[tid * 8];
        else if (tid < 176)
            *(uint4*)&FMB[(long)b * KEP + (tid - 96) * 8] = *(uint4*)&stF[(tid - 96) * 8];
    } else if (bid < BATCH + 1536) {
        // ---- W2 transpose: fi_w -> W2[n][768]; block = (kt, m, chunk) ----
        int bt = bid - BATCH;
        int kt = bt >> 6, m = (bt >> 2) & 15, ch = bt & 3;
        float* tile = smem;   // [32][101]
        for (int i = tid; i < 32 * 25; i += 256) {
            int ql = i / 25, c4 = i - ql * 25;
            int q = kt * 32 + ql;
            float4 v = make_float4(0.f, 0.f, 0.f, 0.f);
            if (q < QQ) v = *(const float4*)&fi_w[(q * MM + m) * DEEP_ + ch * 100 + c4 * 4];
            tile[ql * 101 + c4 * 4 + 0] = v.x; tile[ql * 101 + c4 * 4 + 1] = v.y;
            tile[ql * 101 + c4 * 4 + 2] = v.z; tile[ql * 101 + c4 * 4 + 3] = v.w;
        }
        __syncthreads();
        for (int i = tid; i < 100 * 4; i += 256) {
            int lc = i >> 2, cq = i & 3;
            int kcol = ch * 100 + lc;
            unsigned r[4];
#pragma unroll
            for (int j = 0; j < 4; ++j)
                r[j] = pack2(tile[(cq * 8 + 2 * j) * 101 + lc], tile[(cq * 8 + 2 * j + 1) * 101 + lc]);
            *(uint4*)&W2[(long)(kcol * 16 + m) * QPAD + kt * 32 + cq * 8] =
                make_uint4(r[0], r[1], r[2], r[3]);
        }
    } else {
        // ---- WE transpose: emb_w -> WE[n][640]; block = (kt, chunk) ----
        int bt = bid - BATCH - 1536;
        int kt = bt >> 2, ch = bt & 3;
        float* tile = smem;   // [32][129]
        for (int i = tid; i < 32 * 32; i += 256) {
            int kl = i >> 5, c4 = i & 31;
            int k = kt * 32 + kl;
            int n = ch * 128 + c4 * 4;
            float4 v = make_float4(0.f, 0.f, 0.f, 0.f);
            if (k < KE && n < DEEP_) v = *(const float4*)&emb_w[k * DEEP_ + n];
            tile[kl * 129 + c4 * 4 + 0] = v.x; tile[kl * 129 + c4 * 4 + 1] = v.y;
            tile[kl * 129 + c4 * 4 + 2] = v.z; tile[kl * 129 + c4 * 4 + 3] = v.w;
        }
        __syncthreads();
        for (int i = tid; i < 128 * 4; i += 256) {
            int nl = i >> 2, cq = i & 3;
            int n = ch * 128 + nl;
            uint4 o = make_uint4(0, 0, 0, 0);
            if (n < DEEP_) {
                unsigned r[4];
#pragma unroll
                for (int j = 0; j < 4; ++j)
                    r[j] = pack2(tile[(cq * 8 + 2 * j) * 129 + nl], tile[(cq * 8 + 2 * j + 1) * 129 + nl]);
                o = make_uint4(r[0], r[1], r[2], r[3]);
            }
            if (n < NEP)
                *(uint4*)&WE[(long)n * KEP + kt * 32 + cq * 8] = o;
        }
    }
}

// ---------------- unified GEMM dispatch ---------------------------------------
// Block tile 256x256, 8 waves of 128x64 (AI = 42.7 FLOP/B -> MFMA-bound vs LDS).
// 3-slot counted-vmcnt pipeline, 4 loads/stage/thread:
//   prologue: stage(0),stage(1) -> 8 in flight; vmcnt(4) drains slot 0.
//   iter t:   stage(t+2) -> 8 in flight; vmcnt(4) drains slot t+1, keeps t+2.
//   tail:     vmcnt(0).
__device__ __forceinline__ void pipeline3(const ushort* p0, const ushort* p1,
                                          const ushort* p2, const ushort* p3,
                                          ushort* lds, int tid, int nt,
                                          int f1b, int f2b, int sw,
                                          f32x4 (*acc)[4]) {
#define STAGEP(SL, T) { \
    ushort* L_ = lds + (SL) * 16384; \
    async16(L_ + tid * 8,         p0 + (T) * 32); \
    async16(L_ + 4096 + tid * 8,  p1 + (T) * 32); \
    async16(L_ + 8192 + tid * 8,  p2 + (T) * 32); \
    async16(L_ + 12288 + tid * 8, p3 + (T) * 32); }
    STAGEP(0, 0); STAGEP(1, 1);
    asm volatile("s_waitcnt vmcnt(4)" ::: "memory");
    __builtin_amdgcn_s_barrier();
    int sl = 0;
    for (int t = 0; t < nt; ++t) {
        __builtin_amdgcn_sched_barrier(0);
        const ushort* cur = lds + sl * 16384;
        bf16x8 f1[8], f2[4];
#pragma unroll
        for (int r = 0; r < 8; ++r) f1[r] = *(const bf16x8*)&cur[f1b + r * 512 + sw];
#pragma unroll
        for (int c = 0; c < 4; ++c) f2[c] = *(const bf16x8*)&cur[f2b + c * 512 + sw];
        int sl2 = sl + 2; if (sl2 >= 3) sl2 -= 3;
        if (t + 2 < nt) STAGEP(sl2, t + 2);
        __builtin_amdgcn_s_setprio(1);
#pragma unroll
        for (int r = 0; r < 8; ++r)
#pragma unroll
            for (int c = 0; c < 4; ++c)
                acc[r][c] = __builtin_amdgcn_mfma_f32_16x16x32_bf16(f1[r], f2[c], acc[r][c], 0, 0, 0);
        __builtin_amdgcn_s_setprio(0);
        if (t + 1 < nt) {
            if (t + 2 < nt) { asm volatile("s_waitcnt vmcnt(4)" ::: "memory"); }
            else            { asm volatile("s_waitcnt vmcnt(0)" ::: "memory"); }
            __builtin_amdgcn_s_barrier();
        }
        sl = sl + 1; if (sl >= 3) sl -= 3;
    }
#undef STAGEP
}

__global__ __launch_bounds__(512, 2) void kgemms(const ushort* __restrict__ Abf,
                                                 const ushort* __restrict__ W2,
                                                 const ushort* __restrict__ FMB,
                                                 const ushort* __restrict__ WE,
                                                 const float* __restrict__ Tmat,
                                                 float* __restrict__ TH,
                                                 float* __restrict__ EMB,
                                                 float* __restrict__ ACC) {
    __shared__ ushort ldsbuf[3 * 16384];   // slot: A[256][32] | B[256][32]
    __shared__ float red[512];
    int tid = threadIdx.x;
    int lane = tid & 63, wid = tid >> 6;
    int wB = wid >> 2;        // 0..1: 128-row side (f1)
    int wS = wid & 3;         // 0..3: 64-row side (f2)
    int kq = lane >> 4, lr = lane & 15;
    int rr = tid >> 2, ac = tid & 3;
    int csw = (ac ^ ((rr >> 1) & 3)) * 8;   // inverse-swizzled global source
    int sw = (kq ^ ((lr >> 1) & 3)) * 8;    // swizzled LDS fragment read
    red[tid] = 0.f;
    f32x4 acc[8][4] = {};
    int wg = blockIdx.x;

    if (wg < 400) {
        // main GEMM, operand-swapped: f1 = W (n, 128-side), f2 = A (b, 64-side)
        int s = (wg & 7) * 50 + (wg >> 3);     // XCD swizzle (400 % 8 == 0)
        int b0 = (s / 25) * 256;
        int n0 = (s % 25) * 256;
        const ushort* p0 = Abf + (long)(b0 + rr) * QPAD + csw;
        const ushort* p1 = Abf + (long)(b0 + 128 + rr) * QPAD + csw;
        const ushort* p2 = W2 + (long)(n0 + rr) * QPAD + csw;
        const ushort* p3 = W2 + (long)(n0 + 128 + rr) * QPAD + csw;
        pipeline3(p0, p1, p2, p3, ldsbuf, tid, NT_,
                  8192 + (wB * 128 + lr) * 32, (wS * 64 + lr) * 32, sw, acc);
        // acc[r][cg][j] = C'[n = n0+wB*128+r*16+kq*4+j][b = b0+wS*64+cg*16+lr]
        float* tbuf = (float*)ldsbuf;          // [256][17] floats, inside slot 0
        float ls[8] = {}, ls2[8] = {};
#pragma unroll
        for (int cg = 0; cg < 4; ++cg) {
            int bloc = wS * 64 + cg * 16 + lr;
            float4 t4 = *(const float4*)&Tmat[(b0 + bloc) * 16 + kq * 4];
#pragma unroll
            for (int r = 0; r < 8; ++r) {
                float v = acc[r][cg][0] * t4.x + acc[r][cg][1] * t4.y +
                          acc[r][cg][2] * t4.z + acc[r][cg][3] * t4.w;
                v += __shfl_xor(v, 16);
                v += __shfl_xor(v, 32);
                ls[r] += v; ls2[r] += v * v;
                if (lane < 16) tbuf[bloc * 17 + wB * 8 + r] = v;
            }
        }
#pragma unroll
        for (int r = 0; r < 8; ++r) {
            float a = ls[r], b2 = ls2[r];
            a += __shfl_xor(a, 8, 16); b2 += __shfl_xor(b2, 8, 16);
            a += __shfl_xor(a, 4, 16); b2 += __shfl_xor(b2, 4, 16);
            a += __shfl_xor(a, 2, 16); b2 += __shfl_xor(b2, 2, 16);
            a += __shfl_xor(a, 1, 16); b2 += __shfl_xor(b2, 1, 16);
            if (lane == 0) {
                atomicAdd(&red[wB * 8 + r], a);
                atomicAdd(&red[16 + wB * 8 + r], b2);
            }
        }
        __syncthreads();
        if (tid < 16) {
            atomicAdd(&ACC[(n0 >> 4) + tid], red[tid]);
            atomicAdd(&ACC[800 + (n0 >> 4) + tid], red[16 + tid]);
        }
        {
            int rowl = tid >> 1, kcb = (tid & 1) * 8;
            float o0 = tbuf[rowl * 17 + kcb + 0];
            float o1 = tbuf[rowl * 17 + kcb + 1];
            float o2 = tbuf[rowl * 17 + kcb + 2];
            float o3 = tbuf[rowl * 17 + kcb + 3];
            float o4 = tbuf[rowl * 17 + kcb + 4];
            float o5 = tbuf[rowl * 17 + kcb + 5];
            float o6 = tbuf[rowl * 17 + kcb + 6];
            float o7 = tbuf[rowl * 17 + kcb + 7];
            float* dst = &TH[(b0 + rowl) * DEEP_ + (n0 >> 4) + kcb];
            *(float4*)dst = make_float4(o0, o1, o2, o3);
            *(float4*)(dst + 4) = make_float4(o4, o5, o6, o7);
        }
    } else {
        // emb GEMM, natural operands: f1 = FMB (b, 128-side), f2 = WE (n, 64-side)
        int e = wg - 400;
        int se = (e & 7) * 4 + (e >> 3);       // 32 % 8 == 0
        int b0 = (se >> 1) * 256;
        int n0 = (se & 1) * 256;
        const ushort* p0 = FMB + (long)(b0 + rr) * KEP + csw;
        const ushort* p1 = FMB + (long)(b0 + 128 + rr) * KEP + csw;
        const ushort* p2 = WE + (long)(n0 + rr) * KEP + csw;
        const ushort* p3 = WE + (long)(n0 + 128 + rr) * KEP + csw;
        pipeline3(p0, p1, p2, p3, ldsbuf, tid, NKTE,
                  (wB * 128 + lr) * 32, 8192 + (wS * 64 + lr) * 32, sw, acc);
        // acc[r][cg][j] = C[b = b0+wB*128+r*16+kq*4+j][n = n0+wS*64+cg*16+lr]
#pragma unroll
        for (int cg = 0; cg < 4; ++cg) {
            int ncl = wS * 64 + cg * 16 + lr;
            int nc = n0 + ncl;
            float ls = 0.f, ls2 = 0.f;
#pragma unroll
            for (int r = 0; r < 8; ++r) {
#pragma unroll
                for (int j = 0; j < 4; ++j) {
                    float v = acc[r][cg][j];
                    int brow = b0 + wB * 128 + r * 16 + kq * 4 + j;
                    if (nc < DEEP_) EMB[brow * DEEP_ + nc] = v;
                    ls += v; ls2 += v * v;
                }
            }
            ls += __shfl_xor(ls, 16);  ls += __shfl_xor(ls, 32);
            ls2 += __shfl_xor(ls2, 16); ls2 += __shfl_xor(ls2, 32);
            if (lane < 16 && nc < DEEP_) {
                atomicAdd(&red[ncl], ls);
                atomicAdd(&red[256 + ncl], ls2);
            }
        }
        __syncthreads();
        if (tid < 256) {
            int nc = n0 + tid;
            if (nc < DEEP_) {
                atomicAdd(&ACC[400 + nc], red[tid]);
                atomicAdd(&ACC[1200 + nc], red[256 + tid]);
            }
        }
    }
}

// ---------------- final BN + ReLU + FC + sigmoid -------------------------------
__global__ __launch_bounds__(256) void kfinal(const float* __restrict__ fig,
                                              const float* __restrict__ fibeta,
                                              const float* __restrict__ eg,
                                              const float* __restrict__ ebeta,
                                              const float* __restrict__ fcw,
                                              const float* __restrict__ fcb,
                                              const float* __restrict__ ws,
                                              float* __restrict__ out) {
    int b = blockIdx.x, tid = threadIdx.x;
    float part = 0.f;
    if (tid < 200) {
        int c = tid * 4;
        int loc = (c < DEEP_) ? c : c - DEEP_;
        const float* xp = (c < DEEP_) ? &ws[OFF_TH + b * DEEP_ + loc]
                                      : &ws[OFF_EMB + b * DEEP_ + loc];
        float4 x = *(const float4*)xp;
        float4 g = *(const float4*)((c < DEEP_) ? &fig[loc] : &eg[loc]);
        float4 be = *(const float4*)((c < DEEP_) ? &fibeta[loc] : &ebeta[loc]);
        float4 sm = *(const float4*)&ws[OFF_ACC + c];
        float4 sq = *(const float4*)&ws[OFF_ACC + 800 + c];
        float4 w = *(const float4*)&fcw[c];
        const float* xv_ = (const float*)&x; const float* gv = (const float*)&g;
        const float* bev = (const float*)&be; const float* smv = (const float*)&sm;
        const float* sqv = (const float*)&sq; const float* wv = (const float*)&w;
#pragma unroll
        for (int j = 0; j < 4; ++j) {
            float mean = smv[j] * (1.f / BATCH);
            float var = sqv[j] * (1.f / BATCH) - mean * mean;
            float rstd = rsqrtf(var + EPS_);
            float v = fmaxf(gv[j] * (xv_[j] - mean) * rstd + bev[j], 0.f);
            part += v * wv[j];
        }
    }
    __shared__ float red[4];
#pragma unroll
    for (int off = 32; off > 0; off >>= 1) part += __shfl_down(part, off, 64);
    if ((tid & 63) == 0) red[tid >> 6] = part;
    __syncthreads();
    if (tid == 0) {
        float tot = red[0] + red[1] + red[2] + red[3] + fcb[0];
        out[b] = 1.f / (1.f + expf(-tot));
    }
}

extern "C" void kernel_launch(void* const* d_in, const int* in_sizes, int n_in,
                              void* d_out, int out_size, void* d_ws, size_t ws_size,
                              hipStream_t stream) {
    const int*   xi    = (const int*)d_in[0];
    const float* xv    = (const float*)d_in[1];
    const float* emb   = (const float*)d_in[2];
    const float* T3    = (const float*)d_in[3];
    const float* T2    = (const float*)d_in[4];
    const float* gc    = (const float*)d_in[5];
    const float* fi_w  = (const float*)d_in[6];
    const float* fig   = (const float*)d_in[8];
    const float* fibt  = (const float*)d_in[9];
    const float* emb_w = (const float*)d_in[10];
    const float* eg    = (const float*)d_in[12];
    const float* ebt   = (const float*)d_in[13];
    const float* fcw   = (const float*)d_in[14];
    const float* fcb   = (const float*)d_in[15];
    float* ws = (float*)d_ws;
    ushort* Abf = (ushort*)(ws + OFF_ABF);
    ushort* W2  = (ushort*)(ws + OFF_W2);
    ushort* WE  = (ushort*)(ws + OFF_WE);
    ushort* FMB = (ushort*)(ws + OFF_FMB);
    float* out = (float*)d_out;

    hipLaunchKernelGGL(kprep0, dim3(1), dim3(256), 0, stream, T3, T2, ws);
    hipLaunchKernelGGL(kbig, dim3(BATCH + 1536 + 80), dim3(256), 0, stream,
                       xi, xv, emb, gc, fi_w, emb_w, ws, Abf, FMB, W2, WE);
    hipLaunchKernelGGL(kgemms, dim3(432), dim3(512), 0, stream,
                       Abf, W2, FMB, WE, ws + OFF_T, ws + OFF_TH, ws + OFF_EMB, ws + OFF_ACC);
    hipLaunchKernelGGL(kfinal, dim3(BATCH), dim3(256), 0, stream,
                       fig, fibt, eg, ebt, fcw, fcb, ws, out);
}